// Round 14
// baseline (1925.183 us; speedup 1.0000x reference)
//
#include <hip/hip_runtime.h>
#include <cmath>

#define T_STEPS 300
#define NBATCH  256
#define NNEUR   1024
#define BN      (NBATCH * NNEUR)
#define RING_WORDS (NBATCH * NNEUR)   // one ring slot = 256x1024 u32 = 1 MiB

typedef _Float16 f16x8 __attribute__((ext_vector_type(8)));
typedef float    f32x4 __attribute__((ext_vector_type(4)));
typedef unsigned u32x4 __attribute__((ext_vector_type(4)));

// ---- device-scope primitives (commit at / read from the L3 coherence point) -----------
// NOTE (R5/R13 lessons): sc0sc1 is the ONLY safe transport for the exchange — L2-local
// (sc0) polling serves stale lines from the consumer's own L2 and never converges.
__device__ __forceinline__ void st_u4_dev(unsigned* p, u32x4 v) {
    asm volatile("global_store_dwordx4 %0, %1, off sc0 sc1" :: "v"(p), "v"(v) : "memory");
}
__device__ __forceinline__ u32x4 ld_u4_dev(const unsigned* p) {
    u32x4 d; asm volatile("global_load_dwordx4 %0, %1, off sc0 sc1" : "=v"(d) : "v"(p)); return d;
}
__device__ __forceinline__ void st_f4_dev(float* p, f32x4 v) {
    asm volatile("global_store_dwordx4 %0, %1, off sc0 sc1" :: "v"(p), "v"(v) : "memory");
}
__device__ __forceinline__ f32x4 ld_f4_dev(const float* p) {
    f32x4 d; asm volatile("global_load_dwordx4 %0, %1, off sc0 sc1" : "=v"(d) : "v"(p)); return d;
}
__device__ __forceinline__ void st_dw_dev(unsigned* p, unsigned v) {
    asm volatile("global_store_dword %0, %1, off sc0 sc1" :: "v"(p), "v"(v) : "memory");
}
__device__ __forceinline__ unsigned ld_dw_dev(const unsigned* p) {
    unsigned v;
    asm volatile("global_load_dword %0, %1, off sc0 sc1\n\ts_waitcnt vmcnt(0)"
                 : "=v"(v) : "v"(p) : "memory");
    return v;
}
__device__ __forceinline__ void drain_vm() {
    asm volatile("s_waitcnt vmcnt(0)" ::: "memory");
}
// branchless tanh: 1 - 2/(e^{2x}+1); ~1e-6 abs error (margin: threshold/absmax = 4.8x)
__device__ __forceinline__ float fast_tanh(float x) {
    float e = __expf(2.0f * x);
    return 1.0f - 2.0f / (e + 1.0f);
}

// ---- shared prologue helpers -----------------------------------------------------------
__device__ __forceinline__ void detect_mask(const void* mask, int lane,
                                            bool& mask_f32, bool& mask_u8) {
    unsigned mb = 0;
    const unsigned* m32 = (const unsigned*)mask;
    for (int idx = lane; idx < 1024; idx += 64) {
        unsigned v = m32[idx];
        if (v == 0x3F800000u) mb |= 2u;
        else if (v > 1u)      mb |= 1u;
    }
    mask_f32 = __ballot(mb & 2u) != 0ull;
    mask_u8  = !mask_f32 && (__ballot(mb & 1u) != 0ull);
}

__device__ __forceinline__ void build_bfr(const float* W, const void* mask,
                                          bool mask_f32, bool mask_u8,
                                          int m, int w, int l15, int lq, f16x8 bfr[4][8]) {
    #pragma unroll
    for (int ns = 0; ns < 4; ++ns) {
        const size_t rowbase = (size_t)(64 * m + 16 * ns + l15) * NNEUR + 256 * w + 8 * lq;
        #pragma unroll
        for (int kk = 0; kk < 8; ++kk) {
            const size_t i0 = rowbase + 32 * kk;
            f16x8 bv;
            #pragma unroll
            for (int j = 0; j < 8; ++j) {
                const size_t i = i0 + j;
                bool mv;
                if (mask_f32)     mv = ((const float*)mask)[i] != 0.0f;
                else if (mask_u8) mv = ((const unsigned char*)mask)[i] != 0;
                else              mv = ((const int*)mask)[i] != 0;
                bv[j] = (_Float16)(mv ? W[i] : 0.0f);
            }
            bfr[ns][kk] = bv;
        }
    }
}

// ================= FAST kernel: tagged ring, optimistic fetch + subset-probe fallback ===
// word = ((t+1)<<16)|f16bits(r_t); slot = (t+1)&1; ring-reuse skew<=1 proof as R6/R7.
// Steady state: producers published tag t+1 one jitter-window before this poll begins,
// so an optimistic single-shot full fetch (16 dwordx4, validate all tags) usually
// succeeds in ONE L3 round trip. Straggler steps fall back to the R12-proven path:
// probe-spin on 4 vectors (w/ s_sleep backoff) then fetch the remaining 12 once.
__global__ void __launch_bounds__(256, 1)
rnn_fast(const float* __restrict__ inp, const float* __restrict__ nz,
         const float* __restrict__ W, const float* __restrict__ bias,
         const void* __restrict__ mask, unsigned* ring, float* out) {
    const int bid  = blockIdx.x;
    const int g    = bid & 15;
    const int m    = bid >> 4;
    const int tid  = threadIdx.x;
    const int w    = tid >> 6;
    const int lane = tid & 63;
    const int l15  = lane & 15;
    const int lq   = lane >> 4;

    __shared__ __align__(16) float part[2][4][16][68];

    bool mask_f32, mask_u8;
    detect_mask(mask, lane, mask_f32, mask_u8);
    f16x8 bfr[4][8];
    build_bfr(W, mask, mask_f32, mask_u8, m, w, l15, lq, bfr);

    const int orow = tid >> 4;
    const int ocol = (tid & 15) << 2;
    const int grow = 16 * g + orow;
    const int gcol = 64 * m + ocol;
    const float4 b4 = *(const float4*)(bias + gcol);

    float x0 = 0.f, x1 = 0.f, x2 = 0.f, x3 = 0.f;

    // r_0 = tanh(0) = 0: out slice only; t=0 iteration skips the poll entirely.
    *(float4*)(out + (size_t)grow * NNEUR + gcol) = make_float4(0.f, 0.f, 0.f, 0.f);

    const unsigned* rbase = ring + (size_t)(16 * g + l15) * NNEUR + 256 * w + 8 * lq;
    unsigned* const wslot = ring + (size_t)grow * NNEUR + gcol;

    for (int t = 0; t < T_STEPS; ++t) {
        const size_t io = (size_t)t * BN + (size_t)grow * NNEUR + gcol;
        const float4 in4 = *(const float4*)(inp + io);
        const float4 nz4 = *(const float4*)(nz + io);

        f16x8 a[8];
        if (t > 0) {
            const unsigned tgu = (unsigned)(t + 1);
            const unsigned tgt = tgu << 16;
            const unsigned* rb = rbase + (size_t)(tgu & 1) * RING_WORDS;
            u32x4 wv[16];
            bool done;

            {   // ---- optimistic single-shot: fetch all 16, validate all tags (1 RT) ----
                #pragma unroll
                for (int kk = 0; kk < 8; ++kk) {
                    wv[2 * kk]     = ld_u4_dev(rb + 32 * kk);
                    wv[2 * kk + 1] = ld_u4_dev(rb + 32 * kk + 4);
                }
                drain_vm();
                unsigned bad = 0;
                #pragma unroll
                for (int i = 0; i < 16; ++i) {
                    const u32x4 x = wv[i] ^ tgt;          // hi16 == 0 iff fresh
                    bad |= (x[0] | x[1] | x[2] | x[3]) & 0xFFFF0000u;
                }
                done = (__ballot(bad != 0u) == 0ull);
            }

            if (!done) {
                {   // ---- probe spin: 4 dwordx4 + backoff; covers all producer waves ----
                    int budget = 1 << 14;
                    for (;;) {
                        wv[0]  = ld_u4_dev(rb);
                        wv[4]  = ld_u4_dev(rb + 64);
                        wv[8]  = ld_u4_dev(rb + 128);
                        wv[12] = ld_u4_dev(rb + 192);
                        drain_vm();
                        unsigned bad = 0;
                        #pragma unroll
                        for (int i = 0; i < 16; i += 4) {
                            const u32x4 x = wv[i] ^ tgt;
                            bad |= (x[0] | x[1] | x[2] | x[3]) & 0xFFFF0000u;
                        }
                        if (__ballot(bad != 0u) == 0ull) break;
                        if (--budget <= 0) break;         // failsafe: never hang
                        __builtin_amdgcn_s_sleep(1);      // backoff (stability-proven)
                    }
                }
                {   // ---- fetch remaining 12 vectors + validate (expected 1 iter) ----
                    int budget = 1 << 10;
                    for (;;) {
                        wv[1]  = ld_u4_dev(rb + 4);   wv[2]  = ld_u4_dev(rb + 32);
                        wv[3]  = ld_u4_dev(rb + 36);  wv[5]  = ld_u4_dev(rb + 68);
                        wv[6]  = ld_u4_dev(rb + 96);  wv[7]  = ld_u4_dev(rb + 100);
                        wv[9]  = ld_u4_dev(rb + 132); wv[10] = ld_u4_dev(rb + 160);
                        wv[11] = ld_u4_dev(rb + 164); wv[13] = ld_u4_dev(rb + 196);
                        wv[14] = ld_u4_dev(rb + 224); wv[15] = ld_u4_dev(rb + 228);
                        drain_vm();
                        unsigned bad = 0;
                        #pragma unroll
                        for (int i = 0; i < 16; ++i) {
                            if ((i & 3) == 0) continue;   // probe words already validated
                            const u32x4 x = wv[i] ^ tgt;
                            bad |= (x[0] | x[1] | x[2] | x[3]) & 0xFFFF0000u;
                        }
                        if (__ballot(bad != 0u) == 0ull) break;
                        if (--budget <= 0) break;         // failsafe: never hang
                        __builtin_amdgcn_s_sleep(1);
                    }
                }
            }
            #pragma unroll
            for (int kk = 0; kk < 8; ++kk) {
                const u32x4 lo = wv[2 * kk], hi = wv[2 * kk + 1];
                u32x4 p;
                p[0] = (lo[0] & 0xFFFFu) | (lo[1] << 16);
                p[1] = (lo[2] & 0xFFFFu) | (lo[3] << 16);
                p[2] = (hi[0] & 0xFFFFu) | (hi[1] << 16);
                p[3] = (hi[2] & 0xFFFFu) | (hi[3] << 16);
                a[kk] = __builtin_bit_cast(f16x8, p);
            }
        } else {
            #pragma unroll
            for (int kk = 0; kk < 8; ++kk) a[kk] = f16x8{};
        }

        f32x4 acc[4] = {};
        #pragma unroll
        for (int kk = 0; kk < 8; ++kk)
            #pragma unroll
            for (int ns = 0; ns < 4; ++ns)
                acc[ns] = __builtin_amdgcn_mfma_f32_16x16x32_f16(a[kk], bfr[ns][kk], acc[ns], 0, 0, 0);

        const int pb = t & 1;
        #pragma unroll
        for (int ns = 0; ns < 4; ++ns)
            #pragma unroll
            for (int r = 0; r < 4; ++r)
                part[pb][w][(lq << 2) + r][(ns << 4) + l15] = acc[ns][r];

        __syncthreads();

        f32x4 s = *(const f32x4*)&part[pb][0][orow][ocol];
        #pragma unroll
        for (int wv2 = 1; wv2 < 4; ++wv2)
            s += *(const f32x4*)&part[pb][wv2][orow][ocol];

        x0 = 0.9f * x0 + 0.1f * (s[0] + in4.x + b4.x) + 0.003f * nz4.x;
        x1 = 0.9f * x1 + 0.1f * (s[1] + in4.y + b4.y) + 0.003f * nz4.y;
        x2 = 0.9f * x2 + 0.1f * (s[2] + in4.z + b4.z) + 0.003f * nz4.z;
        x3 = 0.9f * x3 + 0.1f * (s[3] + in4.w + b4.w) + 0.003f * nz4.w;

        const float r0 = fast_tanh(x0), r1 = fast_tanh(x1),
                    r2 = fast_tanh(x2), r3 = fast_tanh(x3);

        {   // publish FIRST (critical path: consumers wait on these words)
            const unsigned tg = (unsigned)(t + 2) << 16;
            u32x4 pv;
            pv[0] = tg | (unsigned)__builtin_bit_cast(unsigned short, (_Float16)r0);
            pv[1] = tg | (unsigned)__builtin_bit_cast(unsigned short, (_Float16)r1);
            pv[2] = tg | (unsigned)__builtin_bit_cast(unsigned short, (_Float16)r2);
            pv[3] = tg | (unsigned)__builtin_bit_cast(unsigned short, (_Float16)r3);
            st_u4_dev(wslot + (size_t)((t + 2) & 1) * RING_WORDS, pv);
        }
        *(float4*)(out + (size_t)(t + 1) * BN + (size_t)grow * NNEUR + gcol)
            = make_float4(r0, r1, r2, r3);
    }
}

// ================= SLOW kernel: R4-proven sc0sc1 + flags (4KB ws footprint) =============
__global__ void __launch_bounds__(256, 1)
rnn_slow(const float* __restrict__ inp, const float* __restrict__ nz,
         const float* __restrict__ W, const float* __restrict__ bias,
         const void* __restrict__ mask, unsigned* flags, float* out) {
    const int bid  = blockIdx.x;
    const int g    = bid & 15;
    const int m    = bid >> 4;
    const int tid  = threadIdx.x;
    const int w    = tid >> 6;
    const int lane = tid & 63;
    const int l15  = lane & 15;
    const int lq   = lane >> 4;

    __shared__ __align__(16) float part[2][4][16][68];

    bool mask_f32, mask_u8;
    detect_mask(mask, lane, mask_f32, mask_u8);
    f16x8 bfr[4][8];
    build_bfr(W, mask, mask_f32, mask_u8, m, w, l15, lq, bfr);

    const int orow = tid >> 4;
    const int ocol = (tid & 15) << 2;
    const int grow = 16 * g + orow;
    const int gcol = 64 * m + ocol;
    const float4 b4 = *(const float4*)(bias + gcol);

    float x0 = 0.f, x1 = 0.f, x2 = 0.f, x3 = 0.f;

    unsigned* const myflag  = &flags[(g << 6) + (m << 2) + w];
    unsigned* const myflags = flags + (g << 6) + (w << 4);

    {
        f32x4 z = {0.f, 0.f, 0.f, 0.f};
        st_f4_dev(out + (size_t)grow * NNEUR + gcol, z);
    }
    drain_vm();
    __builtin_amdgcn_sched_barrier(0);
    if (lane == 0) st_dw_dev(myflag, 1u);

    for (int t = 0; t < T_STEPS; ++t) {
        const size_t io = (size_t)t * BN + (size_t)grow * NNEUR + gcol;
        const float4 in4 = *(const float4*)(inp + io);
        const float4 nz4 = *(const float4*)(nz + io);

        {
            const unsigned tgt = (unsigned)(t + 1);
            if (lane < 16) {
                const unsigned* fp = &myflags[lane];
                int spin = 0;
                unsigned v;
                do {
                    v = ld_dw_dev(fp);
                    if (v >= tgt) break;
                    __builtin_amdgcn_s_sleep(1);
                } while (++spin < (1 << 14));
            }
            __builtin_amdgcn_sched_barrier(0);
        }

        f32x4 alo[8], ahi[8];
        {
            const float* ab = out + (size_t)t * BN + (size_t)(16 * g + l15) * NNEUR
                              + 256 * w + 8 * lq;
            #pragma unroll
            for (int kk = 0; kk < 8; ++kk) {
                alo[kk] = ld_f4_dev(ab + 32 * kk);
                ahi[kk] = ld_f4_dev(ab + 32 * kk + 4);
            }
        }
        drain_vm();
        __builtin_amdgcn_sched_barrier(0);

        f16x8 a[8];
        #pragma unroll
        for (int kk = 0; kk < 8; ++kk) {
            f16x8 av;
            av[0] = (_Float16)alo[kk][0]; av[1] = (_Float16)alo[kk][1];
            av[2] = (_Float16)alo[kk][2]; av[3] = (_Float16)alo[kk][3];
            av[4] = (_Float16)ahi[kk][0]; av[5] = (_Float16)ahi[kk][1];
            av[6] = (_Float16)ahi[kk][2]; av[7] = (_Float16)ahi[kk][3];
            a[kk] = av;
        }

        f32x4 acc[4] = {};
        #pragma unroll
        for (int kk = 0; kk < 8; ++kk)
            #pragma unroll
            for (int ns = 0; ns < 4; ++ns)
                acc[ns] = __builtin_amdgcn_mfma_f32_16x16x32_f16(a[kk], bfr[ns][kk], acc[ns], 0, 0, 0);

        const int pb = t & 1;
        #pragma unroll
        for (int ns = 0; ns < 4; ++ns)
            #pragma unroll
            for (int r = 0; r < 4; ++r)
                part[pb][w][(lq << 2) + r][(ns << 4) + l15] = acc[ns][r];

        __syncthreads();

        f32x4 s = *(const f32x4*)&part[pb][0][orow][ocol];
        #pragma unroll
        for (int wv = 1; wv < 4; ++wv)
            s += *(const f32x4*)&part[pb][wv][orow][ocol];

        x0 = 0.9f * x0 + 0.1f * (s[0] + in4.x + b4.x) + 0.003f * nz4.x;
        x1 = 0.9f * x1 + 0.1f * (s[1] + in4.y + b4.y) + 0.003f * nz4.y;
        x2 = 0.9f * x2 + 0.1f * (s[2] + in4.z + b4.z) + 0.003f * nz4.z;
        x3 = 0.9f * x3 + 0.1f * (s[3] + in4.w + b4.w) + 0.003f * nz4.w;

        {
            f32x4 rv = {tanhf(x0), tanhf(x1), tanhf(x2), tanhf(x3)};
            st_f4_dev(out + (size_t)(t + 1) * BN + (size_t)grow * NNEUR + gcol, rv);
        }
        drain_vm();
        __builtin_amdgcn_sched_barrier(0);
        if (lane == 0) st_dw_dev(myflag, (unsigned)(t + 2));
    }
}

extern "C" void kernel_launch(void* const* d_in, const int* in_sizes, int n_in,
                              void* d_out, int out_size, void* d_ws, size_t ws_size,
                              hipStream_t stream) {
    const float* inp  = (const float*)d_in[0];
    const float* nz   = (const float*)d_in[1];
    const float* W    = (const float*)d_in[2];
    const float* bias = (const float*)d_in[3];
    const void*  mask = d_in[4];
    float* out = (float*)d_out;

    const size_t ring_bytes = (size_t)2 * RING_WORDS * sizeof(unsigned);  // 2 MiB
    unsigned* ws = (unsigned*)d_ws;
    void* args[] = {(void*)&inp, (void*)&nz, (void*)&W, (void*)&bias,
                    (void*)&mask, (void*)&ws, (void*)&out};

    if (ws_size >= ring_bytes) {
        // tagged ring + optimistic fetch / subset-probe fallback. Zero every call.
        (void)hipMemsetAsync(ws, 0, ring_bytes, stream);
        hipError_t e = hipLaunchCooperativeKernel((const void*)rnn_fast,
                                                  dim3(256), dim3(256), args, 0, stream);
        if (e != hipSuccess)
            rnn_fast<<<dim3(256), dim3(256), 0, stream>>>(inp, nz, W, bias, mask, ws, out);
    } else {
        // R4-proven slow path: flags only, 4 KiB
        (void)hipMemsetAsync(ws, 0, 4096, stream);
        hipError_t e = hipLaunchCooperativeKernel((const void*)rnn_slow,
                                                  dim3(256), dim3(256), args, 0, stream);
        if (e != hipSuccess)
            rnn_slow<<<dim3(256), dim3(256), 0, stream>>>(inp, nz, W, bias, mask, ws, out);
    }
}

// Round 15
// 1472.236 us; speedup vs baseline: 1.3077x; 1.3077x over previous
//
#include <hip/hip_runtime.h>
#include <cmath>

#define T_STEPS 300
#define NBATCH  256
#define NNEUR   1024
#define BN      (NBATCH * NNEUR)
#define RING_WORDS (NBATCH * NNEUR)   // one ring slot = 256x1024 u32 = 1 MiB

typedef _Float16 f16x8 __attribute__((ext_vector_type(8)));
typedef float    f32x4 __attribute__((ext_vector_type(4)));
typedef unsigned u32x4 __attribute__((ext_vector_type(4)));

// ---- device-scope primitives (commit at / read from the L3 coherence point) -----------
// R5/R13 lessons: sc0sc1 is the ONLY safe transport — L2-local polling serves stale lines.
__device__ __forceinline__ void st_u4_dev(unsigned* p, u32x4 v) {
    asm volatile("global_store_dwordx4 %0, %1, off sc0 sc1" :: "v"(p), "v"(v) : "memory");
}
__device__ __forceinline__ u32x4 ld_u4_dev(const unsigned* p) {
    u32x4 d; asm volatile("global_load_dwordx4 %0, %1, off sc0 sc1" : "=v"(d) : "v"(p)); return d;
}
__device__ __forceinline__ void st_f4_dev(float* p, f32x4 v) {
    asm volatile("global_store_dwordx4 %0, %1, off sc0 sc1" :: "v"(p), "v"(v) : "memory");
}
__device__ __forceinline__ f32x4 ld_f4_dev(const float* p) {
    f32x4 d; asm volatile("global_load_dwordx4 %0, %1, off sc0 sc1" : "=v"(d) : "v"(p)); return d;
}
__device__ __forceinline__ void st_dw_dev(unsigned* p, unsigned v) {
    asm volatile("global_store_dword %0, %1, off sc0 sc1" :: "v"(p), "v"(v) : "memory");
}
__device__ __forceinline__ unsigned ld_dw_dev(const unsigned* p) {
    unsigned v;
    asm volatile("global_load_dword %0, %1, off sc0 sc1\n\ts_waitcnt vmcnt(0)"
                 : "=v"(v) : "v"(p) : "memory");
    return v;
}
__device__ __forceinline__ void drain_vm() {
    asm volatile("s_waitcnt vmcnt(0)" ::: "memory");
}
// branchless tanh: 1 - 2/(e^{2x}+1); ~1e-6 abs error (margin: threshold/absmax = 4.8x)
__device__ __forceinline__ float fast_tanh(float x) {
    float e = __expf(2.0f * x);
    return 1.0f - 2.0f / (e + 1.0f);
}

// ---- shared prologue helpers -----------------------------------------------------------
__device__ __forceinline__ void detect_mask(const void* mask, int lane,
                                            bool& mask_f32, bool& mask_u8) {
    unsigned mb = 0;
    const unsigned* m32 = (const unsigned*)mask;
    for (int idx = lane; idx < 1024; idx += 64) {
        unsigned v = m32[idx];
        if (v == 0x3F800000u) mb |= 2u;
        else if (v > 1u)      mb |= 1u;
    }
    mask_f32 = __ballot(mb & 2u) != 0ull;
    mask_u8  = !mask_f32 && (__ballot(mb & 1u) != 0ull);
}

__device__ __forceinline__ void build_bfr(const float* W, const void* mask,
                                          bool mask_f32, bool mask_u8,
                                          int m, int w, int l15, int lq, f16x8 bfr[4][8]) {
    #pragma unroll
    for (int ns = 0; ns < 4; ++ns) {
        const size_t rowbase = (size_t)(64 * m + 16 * ns + l15) * NNEUR + 256 * w + 8 * lq;
        #pragma unroll
        for (int kk = 0; kk < 8; ++kk) {
            const size_t i0 = rowbase + 32 * kk;
            f16x8 bv;
            #pragma unroll
            for (int j = 0; j < 8; ++j) {
                const size_t i = i0 + j;
                bool mv;
                if (mask_f32)     mv = ((const float*)mask)[i] != 0.0f;
                else if (mask_u8) mv = ((const unsigned char*)mask)[i] != 0;
                else              mv = ((const int*)mask)[i] != 0;
                bv[j] = (_Float16)(mv ? W[i] : 0.0f);
            }
            bfr[ns][kk] = bv;
        }
    }
}

// ================= FAST kernel: tagged ring + minimal probe (1 dwordx4/lane) ============
// word = ((t+1)<<16)|f16bits(r_t); slot = (t+1)&1; ring-reuse skew<=1 proof as R6/R7.
// Probe: wave's 64 lanes redistributed over the detection domain — lane L probes
// row (L&15), member-col-offset 64*(L>>4): ONE dwordx4/lane/iter (1KB/wave, 4x less
// than R12), covering all 16 rows x 4 producer members (= all 16 producer waves).
// Then fetch all 16 vectors ONCE with tag re-validation (self-validating words carry
// correctness; partial-retirement corners just retry the fetch loop).
__global__ void __launch_bounds__(256, 1)
rnn_fast(const float* __restrict__ inp, const float* __restrict__ nz,
         const float* __restrict__ W, const float* __restrict__ bias,
         const void* __restrict__ mask, unsigned* ring, float* out) {
    const int bid  = blockIdx.x;
    const int g    = bid & 15;
    const int m    = bid >> 4;
    const int tid  = threadIdx.x;
    const int w    = tid >> 6;
    const int lane = tid & 63;
    const int l15  = lane & 15;
    const int lq   = lane >> 4;

    __shared__ __align__(16) float part[2][4][16][68];

    bool mask_f32, mask_u8;
    detect_mask(mask, lane, mask_f32, mask_u8);
    f16x8 bfr[4][8];
    build_bfr(W, mask, mask_f32, mask_u8, m, w, l15, lq, bfr);

    const int orow = tid >> 4;
    const int ocol = (tid & 15) << 2;
    const int grow = 16 * g + orow;
    const int gcol = 64 * m + ocol;
    const float4 b4 = *(const float4*)(bias + gcol);

    float x0 = 0.f, x1 = 0.f, x2 = 0.f, x3 = 0.f;

    // r_0 = tanh(0) = 0: out slice only; t=0 iteration skips the poll entirely.
    *(float4*)(out + (size_t)grow * NNEUR + gcol) = make_float4(0.f, 0.f, 0.f, 0.f);

    // data-fetch base: row l15, k = 256w + 8lq (+32kk)
    const unsigned* rbase = ring + (size_t)(16 * g + l15) * NNEUR + 256 * w + 8 * lq;
    // probe base: row l15, k = 256w + 64lq -> one word of every producer wave/member
    const unsigned* pbase = ring + (size_t)(16 * g + l15) * NNEUR + 256 * w + 64 * lq;
    unsigned* const wslot = ring + (size_t)grow * NNEUR + gcol;

    for (int t = 0; t < T_STEPS; ++t) {
        const size_t io = (size_t)t * BN + (size_t)grow * NNEUR + gcol;
        const float4 in4 = *(const float4*)(inp + io);
        const float4 nz4 = *(const float4*)(nz + io);

        f16x8 a[8];
        if (t > 0) {
            const unsigned tgu = (unsigned)(t + 1);
            const unsigned tgt = tgu << 16;
            const size_t slot_off = (size_t)(tgu & 1) * RING_WORDS;
            const unsigned* rb = rbase + slot_off;
            const unsigned* pb = pbase + slot_off;
            u32x4 wv[16];

            {   // ---- minimal probe spin: ONE dwordx4 per lane + backoff ----
                int budget = 1 << 14;
                for (;;) {
                    const u32x4 pv4 = ld_u4_dev(pb);
                    drain_vm();
                    const u32x4 x = pv4 ^ tgt;            // hi16 == 0 iff fresh
                    const unsigned bad = (x[0] | x[1] | x[2] | x[3]) & 0xFFFF0000u;
                    if (__ballot(bad != 0u) == 0ull) break;
                    if (--budget <= 0) break;             // failsafe: never hang
                    __builtin_amdgcn_s_sleep(1);          // backoff (stability-proven)
                }
            }
            {   // ---- bulk fetch all 16 vectors + validate (expected 1 iter) ----
                int budget = 1 << 10;
                for (;;) {
                    #pragma unroll
                    for (int kk = 0; kk < 8; ++kk) {
                        wv[2 * kk]     = ld_u4_dev(rb + 32 * kk);
                        wv[2 * kk + 1] = ld_u4_dev(rb + 32 * kk + 4);
                    }
                    drain_vm();
                    unsigned bad = 0;
                    #pragma unroll
                    for (int i = 0; i < 16; ++i) {
                        const u32x4 x = wv[i] ^ tgt;
                        bad |= (x[0] | x[1] | x[2] | x[3]) & 0xFFFF0000u;
                    }
                    if (__ballot(bad != 0u) == 0ull) break;
                    if (--budget <= 0) break;             // failsafe: never hang
                    __builtin_amdgcn_s_sleep(1);
                }
            }
            #pragma unroll
            for (int kk = 0; kk < 8; ++kk) {
                const u32x4 lo = wv[2 * kk], hi = wv[2 * kk + 1];
                u32x4 p;
                p[0] = (lo[0] & 0xFFFFu) | (lo[1] << 16);
                p[1] = (lo[2] & 0xFFFFu) | (lo[3] << 16);
                p[2] = (hi[0] & 0xFFFFu) | (hi[1] << 16);
                p[3] = (hi[2] & 0xFFFFu) | (hi[3] << 16);
                a[kk] = __builtin_bit_cast(f16x8, p);
            }
        } else {
            #pragma unroll
            for (int kk = 0; kk < 8; ++kk) a[kk] = f16x8{};
        }

        f32x4 acc[4] = {};
        #pragma unroll
        for (int kk = 0; kk < 8; ++kk)
            #pragma unroll
            for (int ns = 0; ns < 4; ++ns)
                acc[ns] = __builtin_amdgcn_mfma_f32_16x16x32_f16(a[kk], bfr[ns][kk], acc[ns], 0, 0, 0);

        const int pb2 = t & 1;
        #pragma unroll
        for (int ns = 0; ns < 4; ++ns)
            #pragma unroll
            for (int r = 0; r < 4; ++r)
                part[pb2][w][(lq << 2) + r][(ns << 4) + l15] = acc[ns][r];

        __syncthreads();

        f32x4 s = *(const f32x4*)&part[pb2][0][orow][ocol];
        #pragma unroll
        for (int wv2 = 1; wv2 < 4; ++wv2)
            s += *(const f32x4*)&part[pb2][wv2][orow][ocol];

        x0 = 0.9f * x0 + 0.1f * (s[0] + in4.x + b4.x) + 0.003f * nz4.x;
        x1 = 0.9f * x1 + 0.1f * (s[1] + in4.y + b4.y) + 0.003f * nz4.y;
        x2 = 0.9f * x2 + 0.1f * (s[2] + in4.z + b4.z) + 0.003f * nz4.z;
        x3 = 0.9f * x3 + 0.1f * (s[3] + in4.w + b4.w) + 0.003f * nz4.w;

        const float r0 = fast_tanh(x0), r1 = fast_tanh(x1),
                    r2 = fast_tanh(x2), r3 = fast_tanh(x3);

        {   // publish FIRST (consumers wait on these words; out store follows)
            const unsigned tg = (unsigned)(t + 2) << 16;
            u32x4 pv;
            pv[0] = tg | (unsigned)__builtin_bit_cast(unsigned short, (_Float16)r0);
            pv[1] = tg | (unsigned)__builtin_bit_cast(unsigned short, (_Float16)r1);
            pv[2] = tg | (unsigned)__builtin_bit_cast(unsigned short, (_Float16)r2);
            pv[3] = tg | (unsigned)__builtin_bit_cast(unsigned short, (_Float16)r3);
            st_u4_dev(wslot + (size_t)((t + 2) & 1) * RING_WORDS, pv);
        }
        *(float4*)(out + (size_t)(t + 1) * BN + (size_t)grow * NNEUR + gcol)
            = make_float4(r0, r1, r2, r3);
    }
}

// ================= SLOW kernel: R4-proven sc0sc1 + flags (4KB ws footprint) =============
__global__ void __launch_bounds__(256, 1)
rnn_slow(const float* __restrict__ inp, const float* __restrict__ nz,
         const float* __restrict__ W, const float* __restrict__ bias,
         const void* __restrict__ mask, unsigned* flags, float* out) {
    const int bid  = blockIdx.x;
    const int g    = bid & 15;
    const int m    = bid >> 4;
    const int tid  = threadIdx.x;
    const int w    = tid >> 6;
    const int lane = tid & 63;
    const int l15  = lane & 15;
    const int lq   = lane >> 4;

    __shared__ __align__(16) float part[2][4][16][68];

    bool mask_f32, mask_u8;
    detect_mask(mask, lane, mask_f32, mask_u8);
    f16x8 bfr[4][8];
    build_bfr(W, mask, mask_f32, mask_u8, m, w, l15, lq, bfr);

    const int orow = tid >> 4;
    const int ocol = (tid & 15) << 2;
    const int grow = 16 * g + orow;
    const int gcol = 64 * m + ocol;
    const float4 b4 = *(const float4*)(bias + gcol);

    float x0 = 0.f, x1 = 0.f, x2 = 0.f, x3 = 0.f;

    unsigned* const myflag  = &flags[(g << 6) + (m << 2) + w];
    unsigned* const myflags = flags + (g << 6) + (w << 4);

    {
        f32x4 z = {0.f, 0.f, 0.f, 0.f};
        st_f4_dev(out + (size_t)grow * NNEUR + gcol, z);
    }
    drain_vm();
    __builtin_amdgcn_sched_barrier(0);
    if (lane == 0) st_dw_dev(myflag, 1u);

    for (int t = 0; t < T_STEPS; ++t) {
        const size_t io = (size_t)t * BN + (size_t)grow * NNEUR + gcol;
        const float4 in4 = *(const float4*)(inp + io);
        const float4 nz4 = *(const float4*)(nz + io);

        {
            const unsigned tgt = (unsigned)(t + 1);
            if (lane < 16) {
                const unsigned* fp = &myflags[lane];
                int spin = 0;
                unsigned v;
                do {
                    v = ld_dw_dev(fp);
                    if (v >= tgt) break;
                    __builtin_amdgcn_s_sleep(1);
                } while (++spin < (1 << 14));
            }
            __builtin_amdgcn_sched_barrier(0);
        }

        f32x4 alo[8], ahi[8];
        {
            const float* ab = out + (size_t)t * BN + (size_t)(16 * g + l15) * NNEUR
                              + 256 * w + 8 * lq;
            #pragma unroll
            for (int kk = 0; kk < 8; ++kk) {
                alo[kk] = ld_f4_dev(ab + 32 * kk);
                ahi[kk] = ld_f4_dev(ab + 32 * kk + 4);
            }
        }
        drain_vm();
        __builtin_amdgcn_sched_barrier(0);

        f16x8 a[8];
        #pragma unroll
        for (int kk = 0; kk < 8; ++kk) {
            f16x8 av;
            av[0] = (_Float16)alo[kk][0]; av[1] = (_Float16)alo[kk][1];
            av[2] = (_Float16)alo[kk][2]; av[3] = (_Float16)alo[kk][3];
            av[4] = (_Float16)ahi[kk][0]; av[5] = (_Float16)ahi[kk][1];
            av[6] = (_Float16)ahi[kk][2]; av[7] = (_Float16)ahi[kk][3];
            a[kk] = av;
        }

        f32x4 acc[4] = {};
        #pragma unroll
        for (int kk = 0; kk < 8; ++kk)
            #pragma unroll
            for (int ns = 0; ns < 4; ++ns)
                acc[ns] = __builtin_amdgcn_mfma_f32_16x16x32_f16(a[kk], bfr[ns][kk], acc[ns], 0, 0, 0);

        const int pb = t & 1;
        #pragma unroll
        for (int ns = 0; ns < 4; ++ns)
            #pragma unroll
            for (int r = 0; r < 4; ++r)
                part[pb][w][(lq << 2) + r][(ns << 4) + l15] = acc[ns][r];

        __syncthreads();

        f32x4 s = *(const f32x4*)&part[pb][0][orow][ocol];
        #pragma unroll
        for (int wv = 1; wv < 4; ++wv)
            s += *(const f32x4*)&part[pb][wv][orow][ocol];

        x0 = 0.9f * x0 + 0.1f * (s[0] + in4.x + b4.x) + 0.003f * nz4.x;
        x1 = 0.9f * x1 + 0.1f * (s[1] + in4.y + b4.y) + 0.003f * nz4.y;
        x2 = 0.9f * x2 + 0.1f * (s[2] + in4.z + b4.z) + 0.003f * nz4.z;
        x3 = 0.9f * x3 + 0.1f * (s[3] + in4.w + b4.w) + 0.003f * nz4.w;

        {
            f32x4 rv = {tanhf(x0), tanhf(x1), tanhf(x2), tanhf(x3)};
            st_f4_dev(out + (size_t)(t + 1) * BN + (size_t)grow * NNEUR + gcol, rv);
        }
        drain_vm();
        __builtin_amdgcn_sched_barrier(0);
        if (lane == 0) st_dw_dev(myflag, (unsigned)(t + 2));
    }
}

extern "C" void kernel_launch(void* const* d_in, const int* in_sizes, int n_in,
                              void* d_out, int out_size, void* d_ws, size_t ws_size,
                              hipStream_t stream) {
    const float* inp  = (const float*)d_in[0];
    const float* nz   = (const float*)d_in[1];
    const float* W    = (const float*)d_in[2];
    const float* bias = (const float*)d_in[3];
    const void*  mask = d_in[4];
    float* out = (float*)d_out;

    const size_t ring_bytes = (size_t)2 * RING_WORDS * sizeof(unsigned);  // 2 MiB
    unsigned* ws = (unsigned*)d_ws;
    void* args[] = {(void*)&inp, (void*)&nz, (void*)&W, (void*)&bias,
                    (void*)&mask, (void*)&ws, (void*)&out};

    if (ws_size >= ring_bytes) {
        // tagged ring + minimal probe. Zero every call (exact-match tags repeat).
        (void)hipMemsetAsync(ws, 0, ring_bytes, stream);
        hipError_t e = hipLaunchCooperativeKernel((const void*)rnn_fast,
                                                  dim3(256), dim3(256), args, 0, stream);
        if (e != hipSuccess)
            rnn_fast<<<dim3(256), dim3(256), 0, stream>>>(inp, nz, W, bias, mask, ws, out);
    } else {
        // R4-proven slow path: flags only, 4 KiB
        (void)hipMemsetAsync(ws, 0, 4096, stream);
        hipError_t e = hipLaunchCooperativeKernel((const void*)rnn_slow,
                                                  dim3(256), dim3(256), args, 0, stream);
        if (e != hipSuccess)
            rnn_slow<<<dim3(256), dim3(256), 0, stream>>>(inp, nz, W, bias, mask, ws, out);
    }
}

// Round 16
// 1160.277 us; speedup vs baseline: 1.6592x; 1.2689x over previous
//
#include <hip/hip_runtime.h>
#include <cmath>

#define T_STEPS 300
#define NBATCH  256
#define NNEUR   1024
#define BN      (NBATCH * NNEUR)
#define RING_PACK (BN / 2)   // packed words per slot (f16x2/word); 2 slots = 1 MiB

typedef _Float16 f16x8 __attribute__((ext_vector_type(8)));
typedef float    f32x4 __attribute__((ext_vector_type(4)));
typedef unsigned u32x4 __attribute__((ext_vector_type(4)));
typedef unsigned u32x2 __attribute__((ext_vector_type(2)));

// ---- device-scope primitives (commit at / read from the L3 coherence point) -----------
// R5/R13 lessons: sc0sc1 is the ONLY safe transport — L2-local polling serves stale lines.
__device__ __forceinline__ void st_u2_dev(unsigned* p, u32x2 v) {
    asm volatile("global_store_dwordx2 %0, %1, off sc0 sc1" :: "v"(p), "v"(v) : "memory");
}
__device__ __forceinline__ u32x4 ld_u4_dev(const unsigned* p) {
    u32x4 d; asm volatile("global_load_dwordx4 %0, %1, off sc0 sc1" : "=v"(d) : "v"(p)); return d;
}
__device__ __forceinline__ void st_f4_dev(float* p, f32x4 v) {
    asm volatile("global_store_dwordx4 %0, %1, off sc0 sc1" :: "v"(p), "v"(v) : "memory");
}
__device__ __forceinline__ f32x4 ld_f4_dev(const float* p) {
    f32x4 d; asm volatile("global_load_dwordx4 %0, %1, off sc0 sc1" : "=v"(d) : "v"(p)); return d;
}
__device__ __forceinline__ void st_dw_dev(unsigned* p, unsigned v) {
    asm volatile("global_store_dword %0, %1, off sc0 sc1" :: "v"(p), "v"(v) : "memory");
}
__device__ __forceinline__ unsigned ld_dw_dev(const unsigned* p) {
    unsigned v;
    asm volatile("global_load_dword %0, %1, off sc0 sc1\n\ts_waitcnt vmcnt(0)"
                 : "=v"(v) : "v"(p) : "memory");
    return v;
}
__device__ __forceinline__ void drain_vm() {
    asm volatile("s_waitcnt vmcnt(0)" ::: "memory");
}
// branchless tanh: 1 - 2/(e^{2x}+1); ~1e-6 abs error (margin: threshold/absmax = 4.8x)
__device__ __forceinline__ float fast_tanh(float x) {
    float e = __expf(2.0f * x);
    return 1.0f - 2.0f / (e + 1.0f);
}

// ---- shared prologue helpers -----------------------------------------------------------
__device__ __forceinline__ void detect_mask(const void* mask, int lane,
                                            bool& mask_f32, bool& mask_u8) {
    unsigned mb = 0;
    const unsigned* m32 = (const unsigned*)mask;
    for (int idx = lane; idx < 1024; idx += 64) {
        unsigned v = m32[idx];
        if (v == 0x3F800000u) mb |= 2u;
        else if (v > 1u)      mb |= 1u;
    }
    mask_f32 = __ballot(mb & 2u) != 0ull;
    mask_u8  = !mask_f32 && (__ballot(mb & 1u) != 0ull);
}

__device__ __forceinline__ void build_bfr(const float* W, const void* mask,
                                          bool mask_f32, bool mask_u8,
                                          int m, int w, int l15, int lq, f16x8 bfr[4][8]) {
    #pragma unroll
    for (int ns = 0; ns < 4; ++ns) {
        const size_t rowbase = (size_t)(64 * m + 16 * ns + l15) * NNEUR + 256 * w + 8 * lq;
        #pragma unroll
        for (int kk = 0; kk < 8; ++kk) {
            const size_t i0 = rowbase + 32 * kk;
            f16x8 bv;
            #pragma unroll
            for (int j = 0; j < 8; ++j) {
                const size_t i = i0 + j;
                bool mv;
                if (mask_f32)     mv = ((const float*)mask)[i] != 0.0f;
                else if (mask_u8) mv = ((const unsigned char*)mask)[i] != 0;
                else              mv = ((const int*)mask)[i] != 0;
                bv[j] = (_Float16)(mv ? W[i] : 0.0f);
            }
            bfr[ns][kk] = bv;
        }
    }
}

// ================= FAST kernel: epoch-bit packed ring (f16x2/word, 1-bit epoch tag) =====
// |tanh| <= 1 -> bit14 of every f16 value is 0. Word = f16(c0) | f16(c1)<<16, with bits
// 14 and 30 carrying epoch e(tau) = (tau>>1)&1 (tau = step tag). Slot = tau&1; each slot
// is rewritten every 2 steps, so its previous content has the COMPLEMENT epoch ->
// deterministic staleness detection with 1 bit. memset-0 init has e=0; both slots' first
// consumed tags (tau=2,3) expect e=1 -> init reads as stale. Data+validity atomic per
// dword -> ordering-free (R6 invariant). Exchange bytes HALVED vs tag-per-word.
__global__ void __launch_bounds__(256, 1)
rnn_fast(const float* __restrict__ inp, const float* __restrict__ nz,
         const float* __restrict__ W, const float* __restrict__ bias,
         const void* __restrict__ mask, unsigned* ring, float* out) {
    const int bid  = blockIdx.x;
    const int g    = bid & 15;
    const int m    = bid >> 4;
    const int tid  = threadIdx.x;
    const int w    = tid >> 6;
    const int lane = tid & 63;
    const int l15  = lane & 15;
    const int lq   = lane >> 4;

    __shared__ __align__(16) float part[2][4][16][68];

    bool mask_f32, mask_u8;
    detect_mask(mask, lane, mask_f32, mask_u8);
    f16x8 bfr[4][8];
    build_bfr(W, mask, mask_f32, mask_u8, m, w, l15, lq, bfr);

    const int orow = tid >> 4;
    const int ocol = (tid & 15) << 2;
    const int grow = 16 * g + orow;
    const int gcol = 64 * m + ocol;
    const float4 b4 = *(const float4*)(bias + gcol);

    float x0 = 0.f, x1 = 0.f, x2 = 0.f, x3 = 0.f;

    // r_0 = tanh(0) = 0: out slice only; t=0 iteration skips the poll entirely.
    *(float4*)(out + (size_t)grow * NNEUR + gcol) = make_float4(0.f, 0.f, 0.f, 0.f);

    // packed-ring bases (word = 2 cols):
    // fetch: row 16g+l15, word idx 128w + 16kk + 4lq  (cols 256w+32kk+8lq .. +8)
    const unsigned* rbp = ring + (size_t)(16 * g + l15) * (NNEUR / 2) + 128 * w + 4 * lq;
    // probe: lane L -> row 16g+(L&15), member 4w+(L>>4): first word of that member slice
    const unsigned* pbp = ring + (size_t)(16 * g + l15) * (NNEUR / 2) + 32 * (4 * w + lq);
    // publish: row grow, cols gcol..gcol+3 -> words gcol/2, gcol/2+1
    unsigned* const wslot = ring + (size_t)grow * (NNEUR / 2) + (gcol >> 1);

    for (int t = 0; t < T_STEPS; ++t) {
        const size_t io = (size_t)t * BN + (size_t)grow * NNEUR + gcol;
        const float4 in4 = *(const float4*)(inp + io);
        const float4 nz4 = *(const float4*)(nz + io);

        f16x8 a[8];
        if (t > 0) {
            const unsigned tgu = (unsigned)(t + 1);
            const unsigned em  = ((tgu >> 1) & 1u) ? 0x40004000u : 0u;   // expected epoch
            const size_t slot_off = (size_t)(tgu & 1) * RING_PACK;
            const unsigned* rb = rbp + slot_off;
            const unsigned* pb = pbp + slot_off;
            u32x4 wv[8];

            {   // ---- minimal probe spin: ONE dword per lane (covers 16 rows x 4 members) ----
                int budget = 1 << 14;
                for (;;) {
                    const unsigned pv = ld_dw_dev(pb);
                    const unsigned bad = (pv ^ em) & 0x40004000u;        // both epoch bits
                    if (__ballot(bad != 0u) == 0ull) break;
                    if (--budget <= 0) break;             // failsafe: never hang
                    __builtin_amdgcn_s_sleep(1);          // backoff (stability-proven)
                }
            }
            {   // ---- bulk fetch 8 dwordx4 (half of unpacked) + epoch validation ----
                int budget = 1 << 10;
                for (;;) {
                    #pragma unroll
                    for (int kk = 0; kk < 8; ++kk)
                        wv[kk] = ld_u4_dev(rb + 16 * kk);
                    drain_vm();
                    unsigned bad = 0;
                    #pragma unroll
                    for (int kk = 0; kk < 8; ++kk) {
                        const u32x4 x = wv[kk] ^ em;
                        bad |= (x[0] | x[1] | x[2] | x[3]) & 0x40004000u;
                    }
                    if (__ballot(bad != 0u) == 0ull) break;
                    if (--budget <= 0) break;             // failsafe: never hang
                    __builtin_amdgcn_s_sleep(1);
                }
            }
            #pragma unroll
            for (int kk = 0; kk < 8; ++kk) {
                u32x4 p = wv[kk];
                p[0] &= 0xBFFFBFFFu; p[1] &= 0xBFFFBFFFu;   // clear epoch bits ->
                p[2] &= 0xBFFFBFFFu; p[3] &= 0xBFFFBFFFu;   // exact f16 pairs restored
                a[kk] = __builtin_bit_cast(f16x8, p);
            }
        } else {
            #pragma unroll
            for (int kk = 0; kk < 8; ++kk) a[kk] = f16x8{};
        }

        f32x4 acc[4] = {};
        #pragma unroll
        for (int kk = 0; kk < 8; ++kk)
            #pragma unroll
            for (int ns = 0; ns < 4; ++ns)
                acc[ns] = __builtin_amdgcn_mfma_f32_16x16x32_f16(a[kk], bfr[ns][kk], acc[ns], 0, 0, 0);

        const int pb2 = t & 1;
        #pragma unroll
        for (int ns = 0; ns < 4; ++ns)
            #pragma unroll
            for (int r = 0; r < 4; ++r)
                part[pb2][w][(lq << 2) + r][(ns << 4) + l15] = acc[ns][r];

        __syncthreads();

        f32x4 s = *(const f32x4*)&part[pb2][0][orow][ocol];
        #pragma unroll
        for (int wv2 = 1; wv2 < 4; ++wv2)
            s += *(const f32x4*)&part[pb2][wv2][orow][ocol];

        x0 = 0.9f * x0 + 0.1f * (s[0] + in4.x + b4.x) + 0.003f * nz4.x;
        x1 = 0.9f * x1 + 0.1f * (s[1] + in4.y + b4.y) + 0.003f * nz4.y;
        x2 = 0.9f * x2 + 0.1f * (s[2] + in4.z + b4.z) + 0.003f * nz4.z;
        x3 = 0.9f * x3 + 0.1f * (s[3] + in4.w + b4.w) + 0.003f * nz4.w;

        const float r0 = fast_tanh(x0), r1 = fast_tanh(x1),
                    r2 = fast_tanh(x2), r3 = fast_tanh(x3);

        {   // publish FIRST (consumers wait on these words): 2 packed words, epoch bits ORed
            const unsigned e2m = (((unsigned)(t + 2) >> 1) & 1u) ? 0x40004000u : 0u;
            const unsigned h0 = (unsigned)__builtin_bit_cast(unsigned short, (_Float16)r0);
            const unsigned h1 = (unsigned)__builtin_bit_cast(unsigned short, (_Float16)r1);
            const unsigned h2 = (unsigned)__builtin_bit_cast(unsigned short, (_Float16)r2);
            const unsigned h3 = (unsigned)__builtin_bit_cast(unsigned short, (_Float16)r3);
            u32x2 pw;
            pw[0] = (h0 | (h1 << 16)) | e2m;              // bit14 of |tanh|<=1 f16 is 0
            pw[1] = (h2 | (h3 << 16)) | e2m;
            st_u2_dev(wslot + (size_t)((t + 2) & 1) * RING_PACK, pw);
        }
        *(float4*)(out + (size_t)(t + 1) * BN + (size_t)grow * NNEUR + gcol)
            = make_float4(r0, r1, r2, r3);
    }
}

// ================= SLOW kernel: R4-proven sc0sc1 + flags (4KB ws footprint) =============
__global__ void __launch_bounds__(256, 1)
rnn_slow(const float* __restrict__ inp, const float* __restrict__ nz,
         const float* __restrict__ W, const float* __restrict__ bias,
         const void* __restrict__ mask, unsigned* flags, float* out) {
    const int bid  = blockIdx.x;
    const int g    = bid & 15;
    const int m    = bid >> 4;
    const int tid  = threadIdx.x;
    const int w    = tid >> 6;
    const int lane = tid & 63;
    const int l15  = lane & 15;
    const int lq   = lane >> 4;

    __shared__ __align__(16) float part[2][4][16][68];

    bool mask_f32, mask_u8;
    detect_mask(mask, lane, mask_f32, mask_u8);
    f16x8 bfr[4][8];
    build_bfr(W, mask, mask_f32, mask_u8, m, w, l15, lq, bfr);

    const int orow = tid >> 4;
    const int ocol = (tid & 15) << 2;
    const int grow = 16 * g + orow;
    const int gcol = 64 * m + ocol;
    const float4 b4 = *(const float4*)(bias + gcol);

    float x0 = 0.f, x1 = 0.f, x2 = 0.f, x3 = 0.f;

    unsigned* const myflag  = &flags[(g << 6) + (m << 2) + w];
    unsigned* const myflags = flags + (g << 6) + (w << 4);

    {
        f32x4 z = {0.f, 0.f, 0.f, 0.f};
        st_f4_dev(out + (size_t)grow * NNEUR + gcol, z);
    }
    drain_vm();
    __builtin_amdgcn_sched_barrier(0);
    if (lane == 0) st_dw_dev(myflag, 1u);

    for (int t = 0; t < T_STEPS; ++t) {
        const size_t io = (size_t)t * BN + (size_t)grow * NNEUR + gcol;
        const float4 in4 = *(const float4*)(inp + io);
        const float4 nz4 = *(const float4*)(nz + io);

        {
            const unsigned tgt = (unsigned)(t + 1);
            if (lane < 16) {
                const unsigned* fp = &myflags[lane];
                int spin = 0;
                unsigned v;
                do {
                    v = ld_dw_dev(fp);
                    if (v >= tgt) break;
                    __builtin_amdgcn_s_sleep(1);
                } while (++spin < (1 << 14));
            }
            __builtin_amdgcn_sched_barrier(0);
        }

        f32x4 alo[8], ahi[8];
        {
            const float* ab = out + (size_t)t * BN + (size_t)(16 * g + l15) * NNEUR
                              + 256 * w + 8 * lq;
            #pragma unroll
            for (int kk = 0; kk < 8; ++kk) {
                alo[kk] = ld_f4_dev(ab + 32 * kk);
                ahi[kk] = ld_f4_dev(ab + 32 * kk + 4);
            }
        }
        drain_vm();
        __builtin_amdgcn_sched_barrier(0);

        f16x8 a[8];
        #pragma unroll
        for (int kk = 0; kk < 8; ++kk) {
            f16x8 av;
            av[0] = (_Float16)alo[kk][0]; av[1] = (_Float16)alo[kk][1];
            av[2] = (_Float16)alo[kk][2]; av[3] = (_Float16)alo[kk][3];
            av[4] = (_Float16)ahi[kk][0]; av[5] = (_Float16)ahi[kk][1];
            av[6] = (_Float16)ahi[kk][2]; av[7] = (_Float16)ahi[kk][3];
            a[kk] = av;
        }

        f32x4 acc[4] = {};
        #pragma unroll
        for (int kk = 0; kk < 8; ++kk)
            #pragma unroll
            for (int ns = 0; ns < 4; ++ns)
                acc[ns] = __builtin_amdgcn_mfma_f32_16x16x32_f16(a[kk], bfr[ns][kk], acc[ns], 0, 0, 0);

        const int pb = t & 1;
        #pragma unroll
        for (int ns = 0; ns < 4; ++ns)
            #pragma unroll
            for (int r = 0; r < 4; ++r)
                part[pb][w][(lq << 2) + r][(ns << 4) + l15] = acc[ns][r];

        __syncthreads();

        f32x4 s = *(const f32x4*)&part[pb][0][orow][ocol];
        #pragma unroll
        for (int wv = 1; wv < 4; ++wv)
            s += *(const f32x4*)&part[pb][wv][orow][ocol];

        x0 = 0.9f * x0 + 0.1f * (s[0] + in4.x + b4.x) + 0.003f * nz4.x;
        x1 = 0.9f * x1 + 0.1f * (s[1] + in4.y + b4.y) + 0.003f * nz4.y;
        x2 = 0.9f * x2 + 0.1f * (s[2] + in4.z + b4.z) + 0.003f * nz4.z;
        x3 = 0.9f * x3 + 0.1f * (s[3] + in4.w + b4.w) + 0.003f * nz4.w;

        {
            f32x4 rv = {tanhf(x0), tanhf(x1), tanhf(x2), tanhf(x3)};
            st_f4_dev(out + (size_t)(t + 1) * BN + (size_t)grow * NNEUR + gcol, rv);
        }
        drain_vm();
        __builtin_amdgcn_sched_barrier(0);
        if (lane == 0) st_dw_dev(myflag, (unsigned)(t + 2));
    }
}

extern "C" void kernel_launch(void* const* d_in, const int* in_sizes, int n_in,
                              void* d_out, int out_size, void* d_ws, size_t ws_size,
                              hipStream_t stream) {
    const float* inp  = (const float*)d_in[0];
    const float* nz   = (const float*)d_in[1];
    const float* W    = (const float*)d_in[2];
    const float* bias = (const float*)d_in[3];
    const void*  mask = d_in[4];
    float* out = (float*)d_out;

    const size_t ring_bytes = (size_t)2 * RING_PACK * sizeof(unsigned);  // 1 MiB
    unsigned* ws = (unsigned*)d_ws;
    void* args[] = {(void*)&inp, (void*)&nz, (void*)&W, (void*)&bias,
                    (void*)&mask, (void*)&ws, (void*)&out};

    if (ws_size >= ring_bytes) {
        // packed epoch-tag ring. Zero every call (init epoch 0 = stale for first visits).
        (void)hipMemsetAsync(ws, 0, ring_bytes, stream);
        hipError_t e = hipLaunchCooperativeKernel((const void*)rnn_fast,
                                                  dim3(256), dim3(256), args, 0, stream);
        if (e != hipSuccess)
            rnn_fast<<<dim3(256), dim3(256), 0, stream>>>(inp, nz, W, bias, mask, ws, out);
    } else {
        // R4-proven slow path: flags only, 4 KiB
        (void)hipMemsetAsync(ws, 0, 4096, stream);
        hipError_t e = hipLaunchCooperativeKernel((const void*)rnn_slow,
                                                  dim3(256), dim3(256), args, 0, stream);
        if (e != hipSuccess)
            rnn_slow<<<dim3(256), dim3(256), 0, stream>>>(inp, nz, W, bias, mask, ws, out);
    }
}

// Round 17
// 997.655 us; speedup vs baseline: 1.9297x; 1.1630x over previous
//
#include <hip/hip_runtime.h>
#include <cmath>

#define T_STEPS 300
#define NBATCH  256
#define NNEUR   1024
#define BN      (NBATCH * NNEUR)
#define RING_PACK (BN / 2)   // packed words per slot (f16x2/word); 2 slots = 1 MiB

typedef _Float16 f16x8 __attribute__((ext_vector_type(8)));
typedef float    f32x4 __attribute__((ext_vector_type(4)));
typedef unsigned u32x4 __attribute__((ext_vector_type(4)));
typedef unsigned u32x2 __attribute__((ext_vector_type(2)));

// ---- device-scope primitives (commit at / read from the L3 coherence point) -----------
// R5/R13 lessons: sc0sc1 is the ONLY safe transport — L2-local polling serves stale lines.
__device__ __forceinline__ void st_u2_dev(unsigned* p, u32x2 v) {
    asm volatile("global_store_dwordx2 %0, %1, off sc0 sc1" :: "v"(p), "v"(v) : "memory");
}
__device__ __forceinline__ u32x4 ld_u4_dev(const unsigned* p) {
    u32x4 d; asm volatile("global_load_dwordx4 %0, %1, off sc0 sc1" : "=v"(d) : "v"(p)); return d;
}
__device__ __forceinline__ void st_f4_dev(float* p, f32x4 v) {
    asm volatile("global_store_dwordx4 %0, %1, off sc0 sc1" :: "v"(p), "v"(v) : "memory");
}
__device__ __forceinline__ f32x4 ld_f4_dev(const float* p) {
    f32x4 d; asm volatile("global_load_dwordx4 %0, %1, off sc0 sc1" : "=v"(d) : "v"(p)); return d;
}
__device__ __forceinline__ void st_dw_dev(unsigned* p, unsigned v) {
    asm volatile("global_store_dword %0, %1, off sc0 sc1" :: "v"(p), "v"(v) : "memory");
}
__device__ __forceinline__ unsigned ld_dw_dev(const unsigned* p) {
    unsigned v;
    asm volatile("global_load_dword %0, %1, off sc0 sc1\n\ts_waitcnt vmcnt(0)"
                 : "=v"(v) : "v"(p) : "memory");
    return v;
}
__device__ __forceinline__ void drain_vm() {
    asm volatile("s_waitcnt vmcnt(0)" ::: "memory");
}
// branchless tanh: 1 - 2/(e^{2x}+1); ~1e-6 abs error (margin: threshold/absmax = 4.8x)
__device__ __forceinline__ float fast_tanh(float x) {
    float e = __expf(2.0f * x);
    return 1.0f - 2.0f / (e + 1.0f);
}

// ---- shared prologue helpers -----------------------------------------------------------
__device__ __forceinline__ void detect_mask(const void* mask, int lane,
                                            bool& mask_f32, bool& mask_u8) {
    unsigned mb = 0;
    const unsigned* m32 = (const unsigned*)mask;
    for (int idx = lane; idx < 1024; idx += 64) {
        unsigned v = m32[idx];
        if (v == 0x3F800000u) mb |= 2u;
        else if (v > 1u)      mb |= 1u;
    }
    mask_f32 = __ballot(mb & 2u) != 0ull;
    mask_u8  = !mask_f32 && (__ballot(mb & 1u) != 0ull);
}

__device__ __forceinline__ void build_bfr(const float* W, const void* mask,
                                          bool mask_f32, bool mask_u8,
                                          int m, int w, int l15, int lq, f16x8 bfr[4][8]) {
    #pragma unroll
    for (int ns = 0; ns < 4; ++ns) {
        const size_t rowbase = (size_t)(64 * m + 16 * ns + l15) * NNEUR + 256 * w + 8 * lq;
        #pragma unroll
        for (int kk = 0; kk < 8; ++kk) {
            const size_t i0 = rowbase + 32 * kk;
            f16x8 bv;
            #pragma unroll
            for (int j = 0; j < 8; ++j) {
                const size_t i = i0 + j;
                bool mv;
                if (mask_f32)     mv = ((const float*)mask)[i] != 0.0f;
                else if (mask_u8) mv = ((const unsigned char*)mask)[i] != 0;
                else              mv = ((const int*)mask)[i] != 0;
                bv[j] = (_Float16)(mv ? W[i] : 0.0f);
            }
            bfr[ns][kk] = bv;
        }
    }
}

// ================= FAST kernel: epoch-bit packed ring + in-order per-member pipeline ====
// Word = f16(c0)|f16(c1)<<16 with bits14/30 = epoch e(tau)=(tau>>1)&1 (|tanh|<=1 ->
// bit14 of data is 0). Slot = tau&1; previous slot content has complement epoch ->
// 1-bit staleness detection; memset-0 init reads stale. Data+validity atomic per dword.
// NEW (R17): (a) in/nz prefetched one step ahead (their HBM latency was serial on the
// critical-straggler path); (b) members processed IN ORDER 0..3 — each member's 2
// vectors fetched + 8 MFMAs issued as soon as THAT member is ready, overlapping early
// members' compute with late members' wait while keeping R16's exact accumulation
// order (kk ascending) -> bit-identical, deterministic output.
__global__ void __launch_bounds__(256, 1)
rnn_fast(const float* __restrict__ inp, const float* __restrict__ nz,
         const float* __restrict__ W, const float* __restrict__ bias,
         const void* __restrict__ mask, unsigned* ring, float* out) {
    const int bid  = blockIdx.x;
    const int g    = bid & 15;
    const int m    = bid >> 4;
    const int tid  = threadIdx.x;
    const int w    = tid >> 6;
    const int lane = tid & 63;
    const int l15  = lane & 15;
    const int lq   = lane >> 4;

    __shared__ __align__(16) float part[2][4][16][68];

    bool mask_f32, mask_u8;
    detect_mask(mask, lane, mask_f32, mask_u8);
    f16x8 bfr[4][8];
    build_bfr(W, mask, mask_f32, mask_u8, m, w, l15, lq, bfr);

    const int orow = tid >> 4;
    const int ocol = (tid & 15) << 2;
    const int grow = 16 * g + orow;
    const int gcol = 64 * m + ocol;
    const float4 b4 = *(const float4*)(bias + gcol);

    float x0 = 0.f, x1 = 0.f, x2 = 0.f, x3 = 0.f;

    // r_0 = tanh(0) = 0: out slice only; t=0 iteration skips the exchange entirely.
    *(float4*)(out + (size_t)grow * NNEUR + gcol) = make_float4(0.f, 0.f, 0.f, 0.f);

    // packed-ring bases (word = 2 cols):
    // fetch: row 16g+l15, words 128w + 4lq + 16kk; member mm <-> kk in {2mm, 2mm+1}
    const unsigned* rbp = ring + (size_t)(16 * g + l15) * (NNEUR / 2) + 128 * w + 4 * lq;
    // probe: lane (16lq+l15) -> row l15, member lq's first word (covers all 16 producer waves)
    const unsigned* pbp = ring + (size_t)(16 * g + l15) * (NNEUR / 2) + 32 * (4 * w + lq);
    // publish: row grow, cols gcol..gcol+3 -> words gcol/2, gcol/2+1
    unsigned* const wslot = ring + (size_t)grow * (NNEUR / 2) + (gcol >> 1);

    // software-pipelined drive terms: preload step 0
    float4 in4 = *(const float4*)(inp + (size_t)grow * NNEUR + gcol);
    float4 nz4 = *(const float4*)(nz  + (size_t)grow * NNEUR + gcol);

    for (int t = 0; t < T_STEPS; ++t) {
        f32x4 acc[4] = {};

        if (t > 0) {
            const unsigned tgu = (unsigned)(t + 1);
            const unsigned em  = ((tgu >> 1) & 1u) ? 0x40004000u : 0u;   // expected epoch
            const size_t slot_off = (size_t)(tgu & 1) * RING_PACK;
            const unsigned* rb = rbp + slot_off;
            const unsigned* pb = pbp + slot_off;

            #pragma unroll
            for (int mm = 0; mm < 4; ++mm) {
                {   // ---- wait for member mm (1-dword probe sweep, per-member ballot) ----
                    const unsigned long long mmask = 0xFFFFull << (16 * mm);
                    int budget = 1 << 14;
                    for (;;) {
                        const unsigned pv = ld_dw_dev(pb);
                        const unsigned bad = (pv ^ em) & 0x40004000u;
                        if ((__ballot(bad != 0u) & mmask) == 0ull) break;
                        if (--budget <= 0) break;          // failsafe: never hang
                        __builtin_amdgcn_s_sleep(1);       // backoff (stability-proven)
                    }
                }
                // ---- fetch member mm's 2 vectors + epoch validation ----
                u32x4 v0, v1;
                {
                    int fb = 1 << 10;
                    for (;;) {
                        v0 = ld_u4_dev(rb + 32 * mm);
                        v1 = ld_u4_dev(rb + 32 * mm + 16);
                        drain_vm();
                        const unsigned b0 = (v0[0] ^ em) | (v0[1] ^ em) | (v0[2] ^ em) | (v0[3] ^ em);
                        const unsigned b1 = (v1[0] ^ em) | (v1[1] ^ em) | (v1[2] ^ em) | (v1[3] ^ em);
                        const unsigned bad = (b0 | b1) & 0x40004000u;
                        if (__ballot(bad != 0u) == 0ull) break;
                        if (--fb <= 0) break;              // failsafe: never hang
                        __builtin_amdgcn_s_sleep(1);
                    }
                }
                // ---- unpack (clear epoch bits) + 8 MFMA, same kk order as R16 ----
                u32x4 p0, p1;
                p0[0] = v0[0] & 0xBFFFBFFFu; p0[1] = v0[1] & 0xBFFFBFFFu;
                p0[2] = v0[2] & 0xBFFFBFFFu; p0[3] = v0[3] & 0xBFFFBFFFu;
                p1[0] = v1[0] & 0xBFFFBFFFu; p1[1] = v1[1] & 0xBFFFBFFFu;
                p1[2] = v1[2] & 0xBFFFBFFFu; p1[3] = v1[3] & 0xBFFFBFFFu;
                const f16x8 a0 = __builtin_bit_cast(f16x8, p0);
                const f16x8 a1 = __builtin_bit_cast(f16x8, p1);
                #pragma unroll
                for (int ns = 0; ns < 4; ++ns)
                    acc[ns] = __builtin_amdgcn_mfma_f32_16x16x32_f16(a0, bfr[ns][2 * mm], acc[ns], 0, 0, 0);
                #pragma unroll
                for (int ns = 0; ns < 4; ++ns)
                    acc[ns] = __builtin_amdgcn_mfma_f32_16x16x32_f16(a1, bfr[ns][2 * mm + 1], acc[ns], 0, 0, 0);
            }
        }

        // ---- prefetch NEXT step's drive terms (latency hides under reduce/barrier) ----
        const int tn = (t + 1 < T_STEPS) ? (t + 1) : t;
        const size_t ion = (size_t)tn * BN + (size_t)grow * NNEUR + gcol;
        const float4 in_n = *(const float4*)(inp + ion);
        const float4 nz_n = *(const float4*)(nz + ion);

        const int pb2 = t & 1;
        #pragma unroll
        for (int ns = 0; ns < 4; ++ns)
            #pragma unroll
            for (int r = 0; r < 4; ++r)
                part[pb2][w][(lq << 2) + r][(ns << 4) + l15] = acc[ns][r];

        __syncthreads();

        f32x4 s = *(const f32x4*)&part[pb2][0][orow][ocol];
        #pragma unroll
        for (int wv2 = 1; wv2 < 4; ++wv2)
            s += *(const f32x4*)&part[pb2][wv2][orow][ocol];

        x0 = 0.9f * x0 + 0.1f * (s[0] + in4.x + b4.x) + 0.003f * nz4.x;
        x1 = 0.9f * x1 + 0.1f * (s[1] + in4.y + b4.y) + 0.003f * nz4.y;
        x2 = 0.9f * x2 + 0.1f * (s[2] + in4.z + b4.z) + 0.003f * nz4.z;
        x3 = 0.9f * x3 + 0.1f * (s[3] + in4.w + b4.w) + 0.003f * nz4.w;

        const float r0 = fast_tanh(x0), r1 = fast_tanh(x1),
                    r2 = fast_tanh(x2), r3 = fast_tanh(x3);

        {   // publish FIRST (consumers wait on these words): 2 packed words + epoch bits
            const unsigned e2m = (((unsigned)(t + 2) >> 1) & 1u) ? 0x40004000u : 0u;
            const unsigned h0 = (unsigned)__builtin_bit_cast(unsigned short, (_Float16)r0);
            const unsigned h1 = (unsigned)__builtin_bit_cast(unsigned short, (_Float16)r1);
            const unsigned h2 = (unsigned)__builtin_bit_cast(unsigned short, (_Float16)r2);
            const unsigned h3 = (unsigned)__builtin_bit_cast(unsigned short, (_Float16)r3);
            u32x2 pw;
            pw[0] = (h0 | (h1 << 16)) | e2m;
            pw[1] = (h2 | (h3 << 16)) | e2m;
            st_u2_dev(wslot + (size_t)((t + 2) & 1) * RING_PACK, pw);
        }
        *(float4*)(out + (size_t)(t + 1) * BN + (size_t)grow * NNEUR + gcol)
            = make_float4(r0, r1, r2, r3);

        in4 = in_n; nz4 = nz_n;
    }
}

// ================= SLOW kernel: R4-proven sc0sc1 + flags (4KB ws footprint) =============
__global__ void __launch_bounds__(256, 1)
rnn_slow(const float* __restrict__ inp, const float* __restrict__ nz,
         const float* __restrict__ W, const float* __restrict__ bias,
         const void* __restrict__ mask, unsigned* flags, float* out) {
    const int bid  = blockIdx.x;
    const int g    = bid & 15;
    const int m    = bid >> 4;
    const int tid  = threadIdx.x;
    const int w    = tid >> 6;
    const int lane = tid & 63;
    const int l15  = lane & 15;
    const int lq   = lane >> 4;

    __shared__ __align__(16) float part[2][4][16][68];

    bool mask_f32, mask_u8;
    detect_mask(mask, lane, mask_f32, mask_u8);
    f16x8 bfr[4][8];
    build_bfr(W, mask, mask_f32, mask_u8, m, w, l15, lq, bfr);

    const int orow = tid >> 4;
    const int ocol = (tid & 15) << 2;
    const int grow = 16 * g + orow;
    const int gcol = 64 * m + ocol;
    const float4 b4 = *(const float4*)(bias + gcol);

    float x0 = 0.f, x1 = 0.f, x2 = 0.f, x3 = 0.f;

    unsigned* const myflag  = &flags[(g << 6) + (m << 2) + w];
    unsigned* const myflags = flags + (g << 6) + (w << 4);

    {
        f32x4 z = {0.f, 0.f, 0.f, 0.f};
        st_f4_dev(out + (size_t)grow * NNEUR + gcol, z);
    }
    drain_vm();
    __builtin_amdgcn_sched_barrier(0);
    if (lane == 0) st_dw_dev(myflag, 1u);

    for (int t = 0; t < T_STEPS; ++t) {
        const size_t io = (size_t)t * BN + (size_t)grow * NNEUR + gcol;
        const float4 in4 = *(const float4*)(inp + io);
        const float4 nz4 = *(const float4*)(nz + io);

        {
            const unsigned tgt = (unsigned)(t + 1);
            if (lane < 16) {
                const unsigned* fp = &myflags[lane];
                int spin = 0;
                unsigned v;
                do {
                    v = ld_dw_dev(fp);
                    if (v >= tgt) break;
                    __builtin_amdgcn_s_sleep(1);
                } while (++spin < (1 << 14));
            }
            __builtin_amdgcn_sched_barrier(0);
        }

        f32x4 alo[8], ahi[8];
        {
            const float* ab = out + (size_t)t * BN + (size_t)(16 * g + l15) * NNEUR
                              + 256 * w + 8 * lq;
            #pragma unroll
            for (int kk = 0; kk < 8; ++kk) {
                alo[kk] = ld_f4_dev(ab + 32 * kk);
                ahi[kk] = ld_f4_dev(ab + 32 * kk + 4);
            }
        }
        drain_vm();
        __builtin_amdgcn_sched_barrier(0);

        f16x8 a[8];
        #pragma unroll
        for (int kk = 0; kk < 8; ++kk) {
            f16x8 av;
            av[0] = (_Float16)alo[kk][0]; av[1] = (_Float16)alo[kk][1];
            av[2] = (_Float16)alo[kk][2]; av[3] = (_Float16)alo[kk][3];
            av[4] = (_Float16)ahi[kk][0]; av[5] = (_Float16)ahi[kk][1];
            av[6] = (_Float16)ahi[kk][2]; av[7] = (_Float16)ahi[kk][3];
            a[kk] = av;
        }

        f32x4 acc[4] = {};
        #pragma unroll
        for (int kk = 0; kk < 8; ++kk)
            #pragma unroll
            for (int ns = 0; ns < 4; ++ns)
                acc[ns] = __builtin_amdgcn_mfma_f32_16x16x32_f16(a[kk], bfr[ns][kk], acc[ns], 0, 0, 0);

        const int pb = t & 1;
        #pragma unroll
        for (int ns = 0; ns < 4; ++ns)
            #pragma unroll
            for (int r = 0; r < 4; ++r)
                part[pb][w][(lq << 2) + r][(ns << 4) + l15] = acc[ns][r];

        __syncthreads();

        f32x4 s = *(const f32x4*)&part[pb][0][orow][ocol];
        #pragma unroll
        for (int wv = 1; wv < 4; ++wv)
            s += *(const f32x4*)&part[pb][wv][orow][ocol];

        x0 = 0.9f * x0 + 0.1f * (s[0] + in4.x + b4.x) + 0.003f * nz4.x;
        x1 = 0.9f * x1 + 0.1f * (s[1] + in4.y + b4.y) + 0.003f * nz4.y;
        x2 = 0.9f * x2 + 0.1f * (s[2] + in4.z + b4.z) + 0.003f * nz4.z;
        x3 = 0.9f * x3 + 0.1f * (s[3] + in4.w + b4.w) + 0.003f * nz4.w;

        {
            f32x4 rv = {tanhf(x0), tanhf(x1), tanhf(x2), tanhf(x3)};
            st_f4_dev(out + (size_t)(t + 1) * BN + (size_t)grow * NNEUR + gcol, rv);
        }
        drain_vm();
        __builtin_amdgcn_sched_barrier(0);
        if (lane == 0) st_dw_dev(myflag, (unsigned)(t + 2));
    }
}

extern "C" void kernel_launch(void* const* d_in, const int* in_sizes, int n_in,
                              void* d_out, int out_size, void* d_ws, size_t ws_size,
                              hipStream_t stream) {
    const float* inp  = (const float*)d_in[0];
    const float* nz   = (const float*)d_in[1];
    const float* W    = (const float*)d_in[2];
    const float* bias = (const float*)d_in[3];
    const void*  mask = d_in[4];
    float* out = (float*)d_out;

    const size_t ring_bytes = (size_t)2 * RING_PACK * sizeof(unsigned);  // 1 MiB
    unsigned* ws = (unsigned*)d_ws;
    void* args[] = {(void*)&inp, (void*)&nz, (void*)&W, (void*)&bias,
                    (void*)&mask, (void*)&ws, (void*)&out};

    if (ws_size >= ring_bytes) {
        // packed epoch-tag ring. Zero every call (init epoch 0 = stale for first visits).
        (void)hipMemsetAsync(ws, 0, ring_bytes, stream);
        hipError_t e = hipLaunchCooperativeKernel((const void*)rnn_fast,
                                                  dim3(256), dim3(256), args, 0, stream);
        if (e != hipSuccess)
            rnn_fast<<<dim3(256), dim3(256), 0, stream>>>(inp, nz, W, bias, mask, ws, out);
    } else {
        // R4-proven slow path: flags only, 4 KiB
        (void)hipMemsetAsync(ws, 0, 4096, stream);
        hipError_t e = hipLaunchCooperativeKernel((const void*)rnn_slow,
                                                  dim3(256), dim3(256), args, 0, stream);
        if (e != hipSuccess)
            rnn_slow<<<dim3(256), dim3(256), 0, stream>>>(inp, nz, W, bias, mask, ws, out);
    }
}

// Round 18
// 901.903 us; speedup vs baseline: 2.1346x; 1.1062x over previous
//
#include <hip/hip_runtime.h>
#include <cmath>

#define T_STEPS 300
#define NBATCH  256
#define NNEUR   1024
#define BN      (NBATCH * NNEUR)
#define RING_PACK (BN / 2)   // packed words per slot (f16x2/word); 2 slots = 1 MiB

typedef _Float16 f16x8 __attribute__((ext_vector_type(8)));
typedef float    f32x4 __attribute__((ext_vector_type(4)));
typedef unsigned u32x4 __attribute__((ext_vector_type(4)));
typedef unsigned u32x2 __attribute__((ext_vector_type(2)));

// ---- device-scope primitives (commit at / read from the L3 coherence point) -----------
// R5/R13 lessons: sc0sc1 is the ONLY safe transport — L2-local polling serves stale lines.
__device__ __forceinline__ void st_u2_dev(unsigned* p, u32x2 v) {
    asm volatile("global_store_dwordx2 %0, %1, off sc0 sc1" :: "v"(p), "v"(v) : "memory");
}
__device__ __forceinline__ u32x4 ld_u4_dev(const unsigned* p) {
    u32x4 d; asm volatile("global_load_dwordx4 %0, %1, off sc0 sc1" : "=v"(d) : "v"(p)); return d;
}
__device__ __forceinline__ void st_f4_dev(float* p, f32x4 v) {
    asm volatile("global_store_dwordx4 %0, %1, off sc0 sc1" :: "v"(p), "v"(v) : "memory");
}
__device__ __forceinline__ f32x4 ld_f4_dev(const float* p) {
    f32x4 d; asm volatile("global_load_dwordx4 %0, %1, off sc0 sc1" : "=v"(d) : "v"(p)); return d;
}
__device__ __forceinline__ void st_dw_dev(unsigned* p, unsigned v) {
    asm volatile("global_store_dword %0, %1, off sc0 sc1" :: "v"(p), "v"(v) : "memory");
}
__device__ __forceinline__ unsigned ld_dw_dev(const unsigned* p) {
    unsigned v;
    asm volatile("global_load_dword %0, %1, off sc0 sc1\n\ts_waitcnt vmcnt(0)"
                 : "=v"(v) : "v"(p) : "memory");
    return v;
}
__device__ __forceinline__ void drain_vm() {
    asm volatile("s_waitcnt vmcnt(0)" ::: "memory");
}
// branchless tanh: 1 - 2/(e^{2x}+1); ~1e-6 abs error (margin: threshold/absmax = 4.8x)
__device__ __forceinline__ float fast_tanh(float x) {
    float e = __expf(2.0f * x);
    return 1.0f - 2.0f / (e + 1.0f);
}

// ---- shared prologue helpers -----------------------------------------------------------
__device__ __forceinline__ void detect_mask(const void* mask, int lane,
                                            bool& mask_f32, bool& mask_u8) {
    unsigned mb = 0;
    const unsigned* m32 = (const unsigned*)mask;
    for (int idx = lane; idx < 1024; idx += 64) {
        unsigned v = m32[idx];
        if (v == 0x3F800000u) mb |= 2u;
        else if (v > 1u)      mb |= 1u;
    }
    mask_f32 = __ballot(mb & 2u) != 0ull;
    mask_u8  = !mask_f32 && (__ballot(mb & 1u) != 0ull);
}

__device__ __forceinline__ void build_bfr(const float* W, const void* mask,
                                          bool mask_f32, bool mask_u8,
                                          int m, int w, int l15, int lq, f16x8 bfr[4][8]) {
    #pragma unroll
    for (int ns = 0; ns < 4; ++ns) {
        const size_t rowbase = (size_t)(64 * m + 16 * ns + l15) * NNEUR + 256 * w + 8 * lq;
        #pragma unroll
        for (int kk = 0; kk < 8; ++kk) {
            const size_t i0 = rowbase + 32 * kk;
            f16x8 bv;
            #pragma unroll
            for (int j = 0; j < 8; ++j) {
                const size_t i = i0 + j;
                bool mv;
                if (mask_f32)     mv = ((const float*)mask)[i] != 0.0f;
                else if (mask_u8) mv = ((const unsigned char*)mask)[i] != 0;
                else              mv = ((const int*)mask)[i] != 0;
                bv[j] = (_Float16)(mv ? W[i] : 0.0f);
            }
            bfr[ns][kk] = bv;
        }
    }
}

// ================= FAST kernel: epoch-bit packed ring + merged fetch-spin pipeline ======
// Word = f16(c0)|f16(c1)<<16 with bits14/30 = epoch e(tau)=(tau>>1)&1 (|tanh|<=1 ->
// bit14 of data is 0). Slot = tau&1; previous slot content has complement epoch ->
// 1-bit staleness detection; memset-0 init reads stale. Data+validity atomic per dword.
// NEW (R18): the separate 1-dword probe is DELETED — per member, the consumer spins
// directly on the member's 2 data vectors with epoch validation (detection and data
// arrive in the SAME round trip, saving one L3 RT on the critical-member chain; poll
// bytes at 32B/lane/iter are proven non-critical per R12->R15). Rows l15=0..15 span
// all 4 producer waves -> full coverage before the MFMAs consume the data.
__global__ void __launch_bounds__(256, 1)
rnn_fast(const float* __restrict__ inp, const float* __restrict__ nz,
         const float* __restrict__ W, const float* __restrict__ bias,
         const void* __restrict__ mask, unsigned* ring, float* out) {
    const int bid  = blockIdx.x;
    const int g    = bid & 15;
    const int m    = bid >> 4;
    const int tid  = threadIdx.x;
    const int w    = tid >> 6;
    const int lane = tid & 63;
    const int l15  = lane & 15;
    const int lq   = lane >> 4;

    __shared__ __align__(16) float part[2][4][16][68];

    bool mask_f32, mask_u8;
    detect_mask(mask, lane, mask_f32, mask_u8);
    f16x8 bfr[4][8];
    build_bfr(W, mask, mask_f32, mask_u8, m, w, l15, lq, bfr);

    const int orow = tid >> 4;
    const int ocol = (tid & 15) << 2;
    const int grow = 16 * g + orow;
    const int gcol = 64 * m + ocol;
    const float4 b4 = *(const float4*)(bias + gcol);

    float x0 = 0.f, x1 = 0.f, x2 = 0.f, x3 = 0.f;

    // r_0 = tanh(0) = 0: out slice only; t=0 iteration skips the exchange entirely.
    *(float4*)(out + (size_t)grow * NNEUR + gcol) = make_float4(0.f, 0.f, 0.f, 0.f);

    // packed-ring bases (word = 2 cols):
    // fetch: row 16g+l15, words 128w + 4lq + 16kk; member mm <-> kk in {2mm, 2mm+1}
    const unsigned* rbp = ring + (size_t)(16 * g + l15) * (NNEUR / 2) + 128 * w + 4 * lq;
    // publish: row grow, cols gcol..gcol+3 -> words gcol/2, gcol/2+1
    unsigned* const wslot = ring + (size_t)grow * (NNEUR / 2) + (gcol >> 1);

    // software-pipelined drive terms: preload step 0
    float4 in4 = *(const float4*)(inp + (size_t)grow * NNEUR + gcol);
    float4 nz4 = *(const float4*)(nz  + (size_t)grow * NNEUR + gcol);

    for (int t = 0; t < T_STEPS; ++t) {
        f32x4 acc[4] = {};

        if (t > 0) {
            const unsigned tgu = (unsigned)(t + 1);
            const unsigned em  = ((tgu >> 1) & 1u) ? 0x40004000u : 0u;   // expected epoch
            const size_t slot_off = (size_t)(tgu & 1) * RING_PACK;
            const unsigned* rb = rbp + slot_off;

            #pragma unroll
            for (int mm = 0; mm < 4; ++mm) {
                // ---- merged fetch-spin: member mm's 2 vectors, epoch-validated ----
                u32x4 v0, v1;
                {
                    int budget = 1 << 14;
                    for (;;) {
                        v0 = ld_u4_dev(rb + 32 * mm);
                        v1 = ld_u4_dev(rb + 32 * mm + 16);
                        drain_vm();
                        const unsigned b0 = (v0[0] ^ em) | (v0[1] ^ em) | (v0[2] ^ em) | (v0[3] ^ em);
                        const unsigned b1 = (v1[0] ^ em) | (v1[1] ^ em) | (v1[2] ^ em) | (v1[3] ^ em);
                        const unsigned bad = (b0 | b1) & 0x40004000u;
                        if (__ballot(bad != 0u) == 0ull) break;
                        if (--budget <= 0) break;          // failsafe: never hang
                        __builtin_amdgcn_s_sleep(1);       // backoff (stability-proven)
                    }
                }
                // ---- unpack (clear epoch bits) + 8 MFMA, same kk order as R16/R17 ----
                u32x4 p0, p1;
                p0[0] = v0[0] & 0xBFFFBFFFu; p0[1] = v0[1] & 0xBFFFBFFFu;
                p0[2] = v0[2] & 0xBFFFBFFFu; p0[3] = v0[3] & 0xBFFFBFFFu;
                p1[0] = v1[0] & 0xBFFFBFFFu; p1[1] = v1[1] & 0xBFFFBFFFu;
                p1[2] = v1[2] & 0xBFFFBFFFu; p1[3] = v1[3] & 0xBFFFBFFFu;
                const f16x8 a0 = __builtin_bit_cast(f16x8, p0);
                const f16x8 a1 = __builtin_bit_cast(f16x8, p1);
                #pragma unroll
                for (int ns = 0; ns < 4; ++ns)
                    acc[ns] = __builtin_amdgcn_mfma_f32_16x16x32_f16(a0, bfr[ns][2 * mm], acc[ns], 0, 0, 0);
                #pragma unroll
                for (int ns = 0; ns < 4; ++ns)
                    acc[ns] = __builtin_amdgcn_mfma_f32_16x16x32_f16(a1, bfr[ns][2 * mm + 1], acc[ns], 0, 0, 0);
            }
        }

        // ---- prefetch NEXT step's drive terms (latency hides under reduce/barrier) ----
        const int tn = (t + 1 < T_STEPS) ? (t + 1) : t;
        const size_t ion = (size_t)tn * BN + (size_t)grow * NNEUR + gcol;
        const float4 in_n = *(const float4*)(inp + ion);
        const float4 nz_n = *(const float4*)(nz + ion);

        const int pb2 = t & 1;
        #pragma unroll
        for (int ns = 0; ns < 4; ++ns)
            #pragma unroll
            for (int r = 0; r < 4; ++r)
                part[pb2][w][(lq << 2) + r][(ns << 4) + l15] = acc[ns][r];

        __syncthreads();

        f32x4 s = *(const f32x4*)&part[pb2][0][orow][ocol];
        #pragma unroll
        for (int wv2 = 1; wv2 < 4; ++wv2)
            s += *(const f32x4*)&part[pb2][wv2][orow][ocol];

        x0 = 0.9f * x0 + 0.1f * (s[0] + in4.x + b4.x) + 0.003f * nz4.x;
        x1 = 0.9f * x1 + 0.1f * (s[1] + in4.y + b4.y) + 0.003f * nz4.y;
        x2 = 0.9f * x2 + 0.1f * (s[2] + in4.z + b4.z) + 0.003f * nz4.z;
        x3 = 0.9f * x3 + 0.1f * (s[3] + in4.w + b4.w) + 0.003f * nz4.w;

        const float r0 = fast_tanh(x0), r1 = fast_tanh(x1),
                    r2 = fast_tanh(x2), r3 = fast_tanh(x3);

        {   // publish FIRST (consumers wait on these words): 2 packed words + epoch bits
            const unsigned e2m = (((unsigned)(t + 2) >> 1) & 1u) ? 0x40004000u : 0u;
            const unsigned h0 = (unsigned)__builtin_bit_cast(unsigned short, (_Float16)r0);
            const unsigned h1 = (unsigned)__builtin_bit_cast(unsigned short, (_Float16)r1);
            const unsigned h2 = (unsigned)__builtin_bit_cast(unsigned short, (_Float16)r2);
            const unsigned h3 = (unsigned)__builtin_bit_cast(unsigned short, (_Float16)r3);
            u32x2 pw;
            pw[0] = (h0 | (h1 << 16)) | e2m;
            pw[1] = (h2 | (h3 << 16)) | e2m;
            st_u2_dev(wslot + (size_t)((t + 2) & 1) * RING_PACK, pw);
        }
        *(float4*)(out + (size_t)(t + 1) * BN + (size_t)grow * NNEUR + gcol)
            = make_float4(r0, r1, r2, r3);

        in4 = in_n; nz4 = nz_n;
    }
}

// ================= SLOW kernel: R4-proven sc0sc1 + flags (4KB ws footprint) =============
__global__ void __launch_bounds__(256, 1)
rnn_slow(const float* __restrict__ inp, const float* __restrict__ nz,
         const float* __restrict__ W, const float* __restrict__ bias,
         const void* __restrict__ mask, unsigned* flags, float* out) {
    const int bid  = blockIdx.x;
    const int g    = bid & 15;
    const int m    = bid >> 4;
    const int tid  = threadIdx.x;
    const int w    = tid >> 6;
    const int lane = tid & 63;
    const int l15  = lane & 15;
    const int lq   = lane >> 4;

    __shared__ __align__(16) float part[2][4][16][68];

    bool mask_f32, mask_u8;
    detect_mask(mask, lane, mask_f32, mask_u8);
    f16x8 bfr[4][8];
    build_bfr(W, mask, mask_f32, mask_u8, m, w, l15, lq, bfr);

    const int orow = tid >> 4;
    const int ocol = (tid & 15) << 2;
    const int grow = 16 * g + orow;
    const int gcol = 64 * m + ocol;
    const float4 b4 = *(const float4*)(bias + gcol);

    float x0 = 0.f, x1 = 0.f, x2 = 0.f, x3 = 0.f;

    unsigned* const myflag  = &flags[(g << 6) + (m << 2) + w];
    unsigned* const myflags = flags + (g << 6) + (w << 4);

    {
        f32x4 z = {0.f, 0.f, 0.f, 0.f};
        st_f4_dev(out + (size_t)grow * NNEUR + gcol, z);
    }
    drain_vm();
    __builtin_amdgcn_sched_barrier(0);
    if (lane == 0) st_dw_dev(myflag, 1u);

    for (int t = 0; t < T_STEPS; ++t) {
        const size_t io = (size_t)t * BN + (size_t)grow * NNEUR + gcol;
        const float4 in4 = *(const float4*)(inp + io);
        const float4 nz4 = *(const float4*)(nz + io);

        {
            const unsigned tgt = (unsigned)(t + 1);
            if (lane < 16) {
                const unsigned* fp = &myflags[lane];
                int spin = 0;
                unsigned v;
                do {
                    v = ld_dw_dev(fp);
                    if (v >= tgt) break;
                    __builtin_amdgcn_s_sleep(1);
                } while (++spin < (1 << 14));
            }
            __builtin_amdgcn_sched_barrier(0);
        }

        f32x4 alo[8], ahi[8];
        {
            const float* ab = out + (size_t)t * BN + (size_t)(16 * g + l15) * NNEUR
                              + 256 * w + 8 * lq;
            #pragma unroll
            for (int kk = 0; kk < 8; ++kk) {
                alo[kk] = ld_f4_dev(ab + 32 * kk);
                ahi[kk] = ld_f4_dev(ab + 32 * kk + 4);
            }
        }
        drain_vm();
        __builtin_amdgcn_sched_barrier(0);

        f16x8 a[8];
        #pragma unroll
        for (int kk = 0; kk < 8; ++kk) {
            f16x8 av;
            av[0] = (_Float16)alo[kk][0]; av[1] = (_Float16)alo[kk][1];
            av[2] = (_Float16)alo[kk][2]; av[3] = (_Float16)alo[kk][3];
            av[4] = (_Float16)ahi[kk][0]; av[5] = (_Float16)ahi[kk][1];
            av[6] = (_Float16)ahi[kk][2]; av[7] = (_Float16)ahi[kk][3];
            a[kk] = av;
        }

        f32x4 acc[4] = {};
        #pragma unroll
        for (int kk = 0; kk < 8; ++kk)
            #pragma unroll
            for (int ns = 0; ns < 4; ++ns)
                acc[ns] = __builtin_amdgcn_mfma_f32_16x16x32_f16(a[kk], bfr[ns][kk], acc[ns], 0, 0, 0);

        const int pb = t & 1;
        #pragma unroll
        for (int ns = 0; ns < 4; ++ns)
            #pragma unroll
            for (int r = 0; r < 4; ++r)
                part[pb][w][(lq << 2) + r][(ns << 4) + l15] = acc[ns][r];

        __syncthreads();

        f32x4 s = *(const f32x4*)&part[pb][0][orow][ocol];
        #pragma unroll
        for (int wv = 1; wv < 4; ++wv)
            s += *(const f32x4*)&part[pb][wv][orow][ocol];

        x0 = 0.9f * x0 + 0.1f * (s[0] + in4.x + b4.x) + 0.003f * nz4.x;
        x1 = 0.9f * x1 + 0.1f * (s[1] + in4.y + b4.y) + 0.003f * nz4.y;
        x2 = 0.9f * x2 + 0.1f * (s[2] + in4.z + b4.z) + 0.003f * nz4.z;
        x3 = 0.9f * x3 + 0.1f * (s[3] + in4.w + b4.w) + 0.003f * nz4.w;

        {
            f32x4 rv = {tanhf(x0), tanhf(x1), tanhf(x2), tanhf(x3)};
            st_f4_dev(out + (size_t)(t + 1) * BN + (size_t)grow * NNEUR + gcol, rv);
        }
        drain_vm();
        __builtin_amdgcn_sched_barrier(0);
        if (lane == 0) st_dw_dev(myflag, (unsigned)(t + 2));
    }
}

extern "C" void kernel_launch(void* const* d_in, const int* in_sizes, int n_in,
                              void* d_out, int out_size, void* d_ws, size_t ws_size,
                              hipStream_t stream) {
    const float* inp  = (const float*)d_in[0];
    const float* nz   = (const float*)d_in[1];
    const float* W    = (const float*)d_in[2];
    const float* bias = (const float*)d_in[3];
    const void*  mask = d_in[4];
    float* out = (float*)d_out;

    const size_t ring_bytes = (size_t)2 * RING_PACK * sizeof(unsigned);  // 1 MiB
    unsigned* ws = (unsigned*)d_ws;
    void* args[] = {(void*)&inp, (void*)&nz, (void*)&W, (void*)&bias,
                    (void*)&mask, (void*)&ws, (void*)&out};

    if (ws_size >= ring_bytes) {
        // packed epoch-tag ring. Zero every call (init epoch 0 = stale for first visits).
        (void)hipMemsetAsync(ws, 0, ring_bytes, stream);
        hipError_t e = hipLaunchCooperativeKernel((const void*)rnn_fast,
                                                  dim3(256), dim3(256), args, 0, stream);
        if (e != hipSuccess)
            rnn_fast<<<dim3(256), dim3(256), 0, stream>>>(inp, nz, W, bias, mask, ws, out);
    } else {
        // R4-proven slow path: flags only, 4 KiB
        (void)hipMemsetAsync(ws, 0, 4096, stream);
        hipError_t e = hipLaunchCooperativeKernel((const void*)rnn_slow,
                                                  dim3(256), dim3(256), args, 0, stream);
        if (e != hipSuccess)
            rnn_slow<<<dim3(256), dim3(256), 0, stream>>>(inp, nz, W, bias, mask, ws, out);
    }
}

// Round 19
// 801.154 us; speedup vs baseline: 2.4030x; 1.1258x over previous
//
#include <hip/hip_runtime.h>
#include <cmath>

#define T_STEPS 300
#define NBATCH  256
#define NNEUR   1024
#define BN      (NBATCH * NNEUR)
#define RING_PACK (BN / 2)   // packed words per slot (f16x2/word); 2 slots = 1 MiB

typedef _Float16 f16x8 __attribute__((ext_vector_type(8)));
typedef float    f32x4 __attribute__((ext_vector_type(4)));
typedef unsigned u32x4 __attribute__((ext_vector_type(4)));
typedef unsigned u32x2 __attribute__((ext_vector_type(2)));

// ---- device-scope primitives (commit at / read from the L3 coherence point) -----------
// R5/R13 lessons: sc0sc1 is the ONLY safe transport — L2-local polling serves stale lines.
__device__ __forceinline__ void st_u2_dev(unsigned* p, u32x2 v) {
    asm volatile("global_store_dwordx2 %0, %1, off sc0 sc1" :: "v"(p), "v"(v) : "memory");
}
__device__ __forceinline__ u32x4 ld_u4_dev(const unsigned* p) {
    u32x4 d; asm volatile("global_load_dwordx4 %0, %1, off sc0 sc1" : "=v"(d) : "v"(p)); return d;
}
__device__ __forceinline__ void st_f4_dev(float* p, f32x4 v) {
    asm volatile("global_store_dwordx4 %0, %1, off sc0 sc1" :: "v"(p), "v"(v) : "memory");
}
__device__ __forceinline__ f32x4 ld_f4_dev(const float* p) {
    f32x4 d; asm volatile("global_load_dwordx4 %0, %1, off sc0 sc1" : "=v"(d) : "v"(p)); return d;
}
__device__ __forceinline__ void st_dw_dev(unsigned* p, unsigned v) {
    asm volatile("global_store_dword %0, %1, off sc0 sc1" :: "v"(p), "v"(v) : "memory");
}
__device__ __forceinline__ unsigned ld_dw_dev(const unsigned* p) {
    unsigned v;
    asm volatile("global_load_dword %0, %1, off sc0 sc1\n\ts_waitcnt vmcnt(0)"
                 : "=v"(v) : "v"(p) : "memory");
    return v;
}
__device__ __forceinline__ void drain_vm() {
    asm volatile("s_waitcnt vmcnt(0)" ::: "memory");
}
// branchless tanh: 1 - 2/(e^{2x}+1); ~1e-6 abs error (margin: threshold/absmax = 4.8x)
__device__ __forceinline__ float fast_tanh(float x) {
    float e = __expf(2.0f * x);
    return 1.0f - 2.0f / (e + 1.0f);
}

// ---- shared prologue helpers -----------------------------------------------------------
__device__ __forceinline__ void detect_mask(const void* mask, int lane,
                                            bool& mask_f32, bool& mask_u8) {
    unsigned mb = 0;
    const unsigned* m32 = (const unsigned*)mask;
    for (int idx = lane; idx < 1024; idx += 64) {
        unsigned v = m32[idx];
        if (v == 0x3F800000u) mb |= 2u;
        else if (v > 1u)      mb |= 1u;
    }
    mask_f32 = __ballot(mb & 2u) != 0ull;
    mask_u8  = !mask_f32 && (__ballot(mb & 1u) != 0ull);
}

__device__ __forceinline__ void build_bfr(const float* W, const void* mask,
                                          bool mask_f32, bool mask_u8,
                                          int m, int w, int l15, int lq, f16x8 bfr[4][8]) {
    #pragma unroll
    for (int ns = 0; ns < 4; ++ns) {
        const size_t rowbase = (size_t)(64 * m + 16 * ns + l15) * NNEUR + 256 * w + 8 * lq;
        #pragma unroll
        for (int kk = 0; kk < 8; ++kk) {
            const size_t i0 = rowbase + 32 * kk;
            f16x8 bv;
            #pragma unroll
            for (int j = 0; j < 8; ++j) {
                const size_t i = i0 + j;
                bool mv;
                if (mask_f32)     mv = ((const float*)mask)[i] != 0.0f;
                else if (mask_u8) mv = ((const unsigned char*)mask)[i] != 0;
                else              mv = ((const int*)mask)[i] != 0;
                bv[j] = (_Float16)(mv ? W[i] : 0.0f);
            }
            bfr[ns][kk] = bv;
        }
    }
}

// ================= FAST kernel: epoch-bit packed ring + merged ALL-member spin-fetch ====
// Word = f16(c0)|f16(c1)<<16 with bits14/30 = epoch e(tau)=(tau>>1)&1 (|tanh|<=1 ->
// bit14 of data is 0). Slot = tau&1; previous slot content has complement epoch ->
// 1-bit staleness detection; memset-0 init reads stale. Data+validity atomic per dword.
// NEW (R19): ONE spin loop fetches all 8 vectors (all 4 members, 128B/lane) and
// validates all 32 epoch-bit pairs; exit only when EVERY member is fresh. The iteration
// that detects the straggler already carries all members' data -> zero serial RTs after
// the last producer lands (R18's in-order loop paid ~1-3). Poll bytes at 128B/lane are
// in the proven-free range (R12->R15). Unpack/MFMA keep kk-ascending order ->
// bit-identical, deterministic output.
__global__ void __launch_bounds__(256, 1)
rnn_fast(const float* __restrict__ inp, const float* __restrict__ nz,
         const float* __restrict__ W, const float* __restrict__ bias,
         const void* __restrict__ mask, unsigned* ring, float* out) {
    const int bid  = blockIdx.x;
    const int g    = bid & 15;
    const int m    = bid >> 4;
    const int tid  = threadIdx.x;
    const int w    = tid >> 6;
    const int lane = tid & 63;
    const int l15  = lane & 15;
    const int lq   = lane >> 4;

    __shared__ __align__(16) float part[2][4][16][68];

    bool mask_f32, mask_u8;
    detect_mask(mask, lane, mask_f32, mask_u8);
    f16x8 bfr[4][8];
    build_bfr(W, mask, mask_f32, mask_u8, m, w, l15, lq, bfr);

    const int orow = tid >> 4;
    const int ocol = (tid & 15) << 2;
    const int grow = 16 * g + orow;
    const int gcol = 64 * m + ocol;
    const float4 b4 = *(const float4*)(bias + gcol);

    float x0 = 0.f, x1 = 0.f, x2 = 0.f, x3 = 0.f;

    // r_0 = tanh(0) = 0: out slice only; t=0 iteration skips the exchange entirely.
    *(float4*)(out + (size_t)grow * NNEUR + gcol) = make_float4(0.f, 0.f, 0.f, 0.f);

    // packed-ring bases (word = 2 cols):
    // fetch: row 16g+l15, vectors at words 16*k (k=0..7); k=2mm,2mm+1 <-> member mm
    const unsigned* rbp = ring + (size_t)(16 * g + l15) * (NNEUR / 2) + 128 * w + 4 * lq;
    // publish: row grow, cols gcol..gcol+3 -> words gcol/2, gcol/2+1
    unsigned* const wslot = ring + (size_t)grow * (NNEUR / 2) + (gcol >> 1);

    // software-pipelined drive terms: preload step 0
    float4 in4 = *(const float4*)(inp + (size_t)grow * NNEUR + gcol);
    float4 nz4 = *(const float4*)(nz  + (size_t)grow * NNEUR + gcol);

    for (int t = 0; t < T_STEPS; ++t) {
        f32x4 acc[4] = {};

        if (t > 0) {
            const unsigned tgu = (unsigned)(t + 1);
            const unsigned em  = ((tgu >> 1) & 1u) ? 0x40004000u : 0u;   // expected epoch
            const size_t slot_off = (size_t)(tgu & 1) * RING_PACK;
            const unsigned* rb = rbp + slot_off;

            // ---- merged ALL-member spin-fetch: 8 vectors, exit when all 4 fresh ----
            u32x4 v[8];
            {
                int budget = 1 << 14;
                for (;;) {
                    #pragma unroll
                    for (int k = 0; k < 8; ++k)
                        v[k] = ld_u4_dev(rb + 16 * k);
                    drain_vm();
                    unsigned bad = 0;
                    #pragma unroll
                    for (int k = 0; k < 8; ++k) {
                        const u32x4 x = v[k] ^ em;
                        bad |= (x[0] | x[1] | x[2] | x[3]) & 0x40004000u;
                    }
                    if (__ballot(bad != 0u) == 0ull) break;
                    if (--budget <= 0) break;          // failsafe: never hang
                    __builtin_amdgcn_s_sleep(1);       // backoff (stability-proven)
                }
            }
            // ---- unpack (clear epoch bits) + 32 MFMA, same kk order as R16-R18 ----
            #pragma unroll
            for (int kk = 0; kk < 8; ++kk) {
                u32x4 p;
                p[0] = v[kk][0] & 0xBFFFBFFFu; p[1] = v[kk][1] & 0xBFFFBFFFu;
                p[2] = v[kk][2] & 0xBFFFBFFFu; p[3] = v[kk][3] & 0xBFFFBFFFu;
                const f16x8 a = __builtin_bit_cast(f16x8, p);
                #pragma unroll
                for (int ns = 0; ns < 4; ++ns)
                    acc[ns] = __builtin_amdgcn_mfma_f32_16x16x32_f16(a, bfr[ns][kk], acc[ns], 0, 0, 0);
            }
        }

        // ---- prefetch NEXT step's drive terms (latency hides under reduce/barrier) ----
        const int tn = (t + 1 < T_STEPS) ? (t + 1) : t;
        const size_t ion = (size_t)tn * BN + (size_t)grow * NNEUR + gcol;
        const float4 in_n = *(const float4*)(inp + ion);
        const float4 nz_n = *(const float4*)(nz + ion);

        const int pb2 = t & 1;
        #pragma unroll
        for (int ns = 0; ns < 4; ++ns)
            #pragma unroll
            for (int r = 0; r < 4; ++r)
                part[pb2][w][(lq << 2) + r][(ns << 4) + l15] = acc[ns][r];

        __syncthreads();

        f32x4 s = *(const f32x4*)&part[pb2][0][orow][ocol];
        #pragma unroll
        for (int wv2 = 1; wv2 < 4; ++wv2)
            s += *(const f32x4*)&part[pb2][wv2][orow][ocol];

        x0 = 0.9f * x0 + 0.1f * (s[0] + in4.x + b4.x) + 0.003f * nz4.x;
        x1 = 0.9f * x1 + 0.1f * (s[1] + in4.y + b4.y) + 0.003f * nz4.y;
        x2 = 0.9f * x2 + 0.1f * (s[2] + in4.z + b4.z) + 0.003f * nz4.z;
        x3 = 0.9f * x3 + 0.1f * (s[3] + in4.w + b4.w) + 0.003f * nz4.w;

        const float r0 = fast_tanh(x0), r1 = fast_tanh(x1),
                    r2 = fast_tanh(x2), r3 = fast_tanh(x3);

        {   // publish FIRST (consumers wait on these words): 2 packed words + epoch bits
            const unsigned e2m = (((unsigned)(t + 2) >> 1) & 1u) ? 0x40004000u : 0u;
            const unsigned h0 = (unsigned)__builtin_bit_cast(unsigned short, (_Float16)r0);
            const unsigned h1 = (unsigned)__builtin_bit_cast(unsigned short, (_Float16)r1);
            const unsigned h2 = (unsigned)__builtin_bit_cast(unsigned short, (_Float16)r2);
            const unsigned h3 = (unsigned)__builtin_bit_cast(unsigned short, (_Float16)r3);
            u32x2 pw;
            pw[0] = (h0 | (h1 << 16)) | e2m;
            pw[1] = (h2 | (h3 << 16)) | e2m;
            st_u2_dev(wslot + (size_t)((t + 2) & 1) * RING_PACK, pw);
        }
        *(float4*)(out + (size_t)(t + 1) * BN + (size_t)grow * NNEUR + gcol)
            = make_float4(r0, r1, r2, r3);

        in4 = in_n; nz4 = nz_n;
    }
}

// ================= SLOW kernel: R4-proven sc0sc1 + flags (4KB ws footprint) =============
__global__ void __launch_bounds__(256, 1)
rnn_slow(const float* __restrict__ inp, const float* __restrict__ nz,
         const float* __restrict__ W, const float* __restrict__ bias,
         const void* __restrict__ mask, unsigned* flags, float* out) {
    const int bid  = blockIdx.x;
    const int g    = bid & 15;
    const int m    = bid >> 4;
    const int tid  = threadIdx.x;
    const int w    = tid >> 6;
    const int lane = tid & 63;
    const int l15  = lane & 15;
    const int lq   = lane >> 4;

    __shared__ __align__(16) float part[2][4][16][68];

    bool mask_f32, mask_u8;
    detect_mask(mask, lane, mask_f32, mask_u8);
    f16x8 bfr[4][8];
    build_bfr(W, mask, mask_f32, mask_u8, m, w, l15, lq, bfr);

    const int orow = tid >> 4;
    const int ocol = (tid & 15) << 2;
    const int grow = 16 * g + orow;
    const int gcol = 64 * m + ocol;
    const float4 b4 = *(const float4*)(bias + gcol);

    float x0 = 0.f, x1 = 0.f, x2 = 0.f, x3 = 0.f;

    unsigned* const myflag  = &flags[(g << 6) + (m << 2) + w];
    unsigned* const myflags = flags + (g << 6) + (w << 4);

    {
        f32x4 z = {0.f, 0.f, 0.f, 0.f};
        st_f4_dev(out + (size_t)grow * NNEUR + gcol, z);
    }
    drain_vm();
    __builtin_amdgcn_sched_barrier(0);
    if (lane == 0) st_dw_dev(myflag, 1u);

    for (int t = 0; t < T_STEPS; ++t) {
        const size_t io = (size_t)t * BN + (size_t)grow * NNEUR + gcol;
        const float4 in4 = *(const float4*)(inp + io);
        const float4 nz4 = *(const float4*)(nz + io);

        {
            const unsigned tgt = (unsigned)(t + 1);
            if (lane < 16) {
                const unsigned* fp = &myflags[lane];
                int spin = 0;
                unsigned v;
                do {
                    v = ld_dw_dev(fp);
                    if (v >= tgt) break;
                    __builtin_amdgcn_s_sleep(1);
                } while (++spin < (1 << 14));
            }
            __builtin_amdgcn_sched_barrier(0);
        }

        f32x4 alo[8], ahi[8];
        {
            const float* ab = out + (size_t)t * BN + (size_t)(16 * g + l15) * NNEUR
                              + 256 * w + 8 * lq;
            #pragma unroll
            for (int kk = 0; kk < 8; ++kk) {
                alo[kk] = ld_f4_dev(ab + 32 * kk);
                ahi[kk] = ld_f4_dev(ab + 32 * kk + 4);
            }
        }
        drain_vm();
        __builtin_amdgcn_sched_barrier(0);

        f16x8 a[8];
        #pragma unroll
        for (int kk = 0; kk < 8; ++kk) {
            f16x8 av;
            av[0] = (_Float16)alo[kk][0]; av[1] = (_Float16)alo[kk][1];
            av[2] = (_Float16)alo[kk][2]; av[3] = (_Float16)alo[kk][3];
            av[4] = (_Float16)ahi[kk][0]; av[5] = (_Float16)ahi[kk][1];
            av[6] = (_Float16)ahi[kk][2]; av[7] = (_Float16)ahi[kk][3];
            a[kk] = av;
        }

        f32x4 acc[4] = {};
        #pragma unroll
        for (int kk = 0; kk < 8; ++kk)
            #pragma unroll
            for (int ns = 0; ns < 4; ++ns)
                acc[ns] = __builtin_amdgcn_mfma_f32_16x16x32_f16(a[kk], bfr[ns][kk], acc[ns], 0, 0, 0);

        const int pb = t & 1;
        #pragma unroll
        for (int ns = 0; ns < 4; ++ns)
            #pragma unroll
            for (int r = 0; r < 4; ++r)
                part[pb][w][(lq << 2) + r][(ns << 4) + l15] = acc[ns][r];

        __syncthreads();

        f32x4 s = *(const f32x4*)&part[pb][0][orow][ocol];
        #pragma unroll
        for (int wv = 1; wv < 4; ++wv)
            s += *(const f32x4*)&part[pb][wv][orow][ocol];

        x0 = 0.9f * x0 + 0.1f * (s[0] + in4.x + b4.x) + 0.003f * nz4.x;
        x1 = 0.9f * x1 + 0.1f * (s[1] + in4.y + b4.y) + 0.003f * nz4.y;
        x2 = 0.9f * x2 + 0.1f * (s[2] + in4.z + b4.z) + 0.003f * nz4.z;
        x3 = 0.9f * x3 + 0.1f * (s[3] + in4.w + b4.w) + 0.003f * nz4.w;

        {
            f32x4 rv = {tanhf(x0), tanhf(x1), tanhf(x2), tanhf(x3)};
            st_f4_dev(out + (size_t)(t + 1) * BN + (size_t)grow * NNEUR + gcol, rv);
        }
        drain_vm();
        __builtin_amdgcn_sched_barrier(0);
        if (lane == 0) st_dw_dev(myflag, (unsigned)(t + 2));
    }
}

extern "C" void kernel_launch(void* const* d_in, const int* in_sizes, int n_in,
                              void* d_out, int out_size, void* d_ws, size_t ws_size,
                              hipStream_t stream) {
    const float* inp  = (const float*)d_in[0];
    const float* nz   = (const float*)d_in[1];
    const float* W    = (const float*)d_in[2];
    const float* bias = (const float*)d_in[3];
    const void*  mask = d_in[4];
    float* out = (float*)d_out;

    const size_t ring_bytes = (size_t)2 * RING_PACK * sizeof(unsigned);  // 1 MiB
    unsigned* ws = (unsigned*)d_ws;
    void* args[] = {(void*)&inp, (void*)&nz, (void*)&W, (void*)&bias,
                    (void*)&mask, (void*)&ws, (void*)&out};

    if (ws_size >= ring_bytes) {
        // packed epoch-tag ring. Zero every call (init epoch 0 = stale for first visits).
        (void)hipMemsetAsync(ws, 0, ring_bytes, stream);
        hipError_t e = hipLaunchCooperativeKernel((const void*)rnn_fast,
                                                  dim3(256), dim3(256), args, 0, stream);
        if (e != hipSuccess)
            rnn_fast<<<dim3(256), dim3(256), 0, stream>>>(inp, nz, W, bias, mask, ws, out);
    } else {
        // R4-proven slow path: flags only, 4 KiB
        (void)hipMemsetAsync(ws, 0, 4096, stream);
        hipError_t e = hipLaunchCooperativeKernel((const void*)rnn_slow,
                                                  dim3(256), dim3(256), args, 0, stream);
        if (e != hipSuccess)
            rnn_slow<<<dim3(256), dim3(256), 0, stream>>>(inp, nz, W, bias, mask, ws, out);
    }
}

// Round 22
// 797.805 us; speedup vs baseline: 2.4131x; 1.0042x over previous
//
#include <hip/hip_runtime.h>
#include <cmath>

#define T_STEPS 300
#define NBATCH  256
#define NNEUR   1024
#define BN      (NBATCH * NNEUR)
#define RING_PACK (BN / 2)   // packed words per slot (f16x2/word); 2 slots = 1 MiB

typedef _Float16 f16x8 __attribute__((ext_vector_type(8)));
typedef float    f32x4 __attribute__((ext_vector_type(4)));
typedef unsigned u32x4 __attribute__((ext_vector_type(4)));
typedef unsigned u32x2 __attribute__((ext_vector_type(2)));

// ---- device-scope primitives (commit at / read from the L3 coherence point) -----------
// R5/R13 lessons: sc0sc1 is the ONLY safe transport — L2-local polling serves stale lines.
// R21 lesson: partial-vmcnt dual-batch pipelines are NOT safely expressible at HIP source
// level (compiler inserts reg moves between asm loads and manual waitcnt) — single-batch
// load -> vmcnt(0) -> immediate-use is the only safe spin shape.
__device__ __forceinline__ void st_u2_dev(unsigned* p, u32x2 v) {
    asm volatile("global_store_dwordx2 %0, %1, off sc0 sc1" :: "v"(p), "v"(v) : "memory");
}
__device__ __forceinline__ u32x4 ld_u4_dev(const unsigned* p) {
    u32x4 d; asm volatile("global_load_dwordx4 %0, %1, off sc0 sc1" : "=v"(d) : "v"(p)); return d;
}
__device__ __forceinline__ void st_f4_dev(float* p, f32x4 v) {
    asm volatile("global_store_dwordx4 %0, %1, off sc0 sc1" :: "v"(p), "v"(v) : "memory");
}
__device__ __forceinline__ f32x4 ld_f4_dev(const float* p) {
    f32x4 d; asm volatile("global_load_dwordx4 %0, %1, off sc0 sc1" : "=v"(d) : "v"(p)); return d;
}
__device__ __forceinline__ void st_dw_dev(unsigned* p, unsigned v) {
    asm volatile("global_store_dword %0, %1, off sc0 sc1" :: "v"(p), "v"(v) : "memory");
}
__device__ __forceinline__ unsigned ld_dw_dev(const unsigned* p) {
    unsigned v;
    asm volatile("global_load_dword %0, %1, off sc0 sc1\n\ts_waitcnt vmcnt(0)"
                 : "=v"(v) : "v"(p) : "memory");
    return v;
}
__device__ __forceinline__ void drain_vm() {
    asm volatile("s_waitcnt vmcnt(0)" ::: "memory");
}
// branchless tanh: 1 - 2/(e^{2x}+1); ~1e-6 abs error (margin: threshold/absmax = 4.8x)
__device__ __forceinline__ float fast_tanh(float x) {
    float e = __expf(2.0f * x);
    return 1.0f - 2.0f / (e + 1.0f);
}

// ---- shared prologue helpers -----------------------------------------------------------
__device__ __forceinline__ void detect_mask(const void* mask, int lane,
                                            bool& mask_f32, bool& mask_u8) {
    unsigned mb = 0;
    const unsigned* m32 = (const unsigned*)mask;
    for (int idx = lane; idx < 1024; idx += 64) {
        unsigned v = m32[idx];
        if (v == 0x3F800000u) mb |= 2u;
        else if (v > 1u)      mb |= 1u;
    }
    mask_f32 = __ballot(mb & 2u) != 0ull;
    mask_u8  = !mask_f32 && (__ballot(mb & 1u) != 0ull);
}

__device__ __forceinline__ void build_bfr(const float* W, const void* mask,
                                          bool mask_f32, bool mask_u8,
                                          int m, int w, int l15, int lq, f16x8 bfr[4][8]) {
    #pragma unroll
    for (int ns = 0; ns < 4; ++ns) {
        const size_t rowbase = (size_t)(64 * m + 16 * ns + l15) * NNEUR + 256 * w + 8 * lq;
        #pragma unroll
        for (int kk = 0; kk < 8; ++kk) {
            const size_t i0 = rowbase + 32 * kk;
            f16x8 bv;
            #pragma unroll
            for (int j = 0; j < 8; ++j) {
                const size_t i = i0 + j;
                bool mv;
                if (mask_f32)     mv = ((const float*)mask)[i] != 0.0f;
                else if (mask_u8) mv = ((const unsigned char*)mask)[i] != 0;
                else              mv = ((const int*)mask)[i] != 0;
                bv[j] = (_Float16)(mv ? W[i] : 0.0f);
            }
            bfr[ns][kk] = bv;
        }
    }
}

// ================= FAST kernel: epoch-bit packed ring + merged ALL-member spin-fetch ====
// Word = f16(c0)|f16(c1)<<16 with bits14/30 = epoch e(tau)=(tau>>1)&1 (|tanh|<=1 ->
// bit14 of data is 0). Slot = tau&1; previous slot content has complement epoch ->
// 1-bit staleness detection; memset-0 init reads stale. Data+validity atomic per dword.
// R19 (proven 801us): ONE spin loop fetches all 8 vectors (all 4 members, 128B/lane)
// and validates all 32 epoch-bit pairs; exit only when EVERY member is fresh. The
// iteration that detects the straggler already carries all members' data -> zero
// serial RTs after the last producer lands. Accumulation order kk-ascending ->
// bit-identical, deterministic output.
__global__ void __launch_bounds__(256, 1)
rnn_fast(const float* __restrict__ inp, const float* __restrict__ nz,
         const float* __restrict__ W, const float* __restrict__ bias,
         const void* __restrict__ mask, unsigned* ring, float* out) {
    const int bid  = blockIdx.x;
    const int g    = bid & 15;
    const int m    = bid >> 4;
    const int tid  = threadIdx.x;
    const int w    = tid >> 6;
    const int lane = tid & 63;
    const int l15  = lane & 15;
    const int lq   = lane >> 4;

    __shared__ __align__(16) float part[2][4][16][68];

    bool mask_f32, mask_u8;
    detect_mask(mask, lane, mask_f32, mask_u8);
    f16x8 bfr[4][8];
    build_bfr(W, mask, mask_f32, mask_u8, m, w, l15, lq, bfr);

    const int orow = tid >> 4;
    const int ocol = (tid & 15) << 2;
    const int grow = 16 * g + orow;
    const int gcol = 64 * m + ocol;
    const float4 b4 = *(const float4*)(bias + gcol);

    float x0 = 0.f, x1 = 0.f, x2 = 0.f, x3 = 0.f;

    // r_0 = tanh(0) = 0: out slice only; t=0 iteration skips the exchange entirely.
    *(float4*)(out + (size_t)grow * NNEUR + gcol) = make_float4(0.f, 0.f, 0.f, 0.f);

    // packed-ring bases (word = 2 cols):
    // fetch: row 16g+l15, vectors at words 16*k (k=0..7); k=2mm,2mm+1 <-> member mm
    const unsigned* rbp = ring + (size_t)(16 * g + l15) * (NNEUR / 2) + 128 * w + 4 * lq;
    // publish: row grow, cols gcol..gcol+3 -> words gcol/2, gcol/2+1
    unsigned* const wslot = ring + (size_t)grow * (NNEUR / 2) + (gcol >> 1);

    // software-pipelined drive terms: preload step 0
    float4 in4 = *(const float4*)(inp + (size_t)grow * NNEUR + gcol);
    float4 nz4 = *(const float4*)(nz  + (size_t)grow * NNEUR + gcol);

    for (int t = 0; t < T_STEPS; ++t) {
        f32x4 acc[4] = {};

        if (t > 0) {
            const unsigned tgu = (unsigned)(t + 1);
            const unsigned em  = ((tgu >> 1) & 1u) ? 0x40004000u : 0u;   // expected epoch
            const size_t slot_off = (size_t)(tgu & 1) * RING_PACK;
            const unsigned* rb = rbp + slot_off;

            // ---- merged ALL-member spin-fetch: 8 vectors, exit when all 4 fresh ----
            u32x4 v[8];
            {
                int budget = 1 << 14;
                for (;;) {
                    #pragma unroll
                    for (int k = 0; k < 8; ++k)
                        v[k] = ld_u4_dev(rb + 16 * k);
                    drain_vm();
                    unsigned bad = 0;
                    #pragma unroll
                    for (int k = 0; k < 8; ++k) {
                        const u32x4 x = v[k] ^ em;
                        bad |= (x[0] | x[1] | x[2] | x[3]) & 0x40004000u;
                    }
                    if (__ballot(bad != 0u) == 0ull) break;
                    if (--budget <= 0) break;          // failsafe: never hang
                    __builtin_amdgcn_s_sleep(1);       // backoff (stability-proven)
                }
            }
            // ---- unpack (clear epoch bits) + 32 MFMA, same kk order as R16-R18 ----
            #pragma unroll
            for (int kk = 0; kk < 8; ++kk) {
                u32x4 p;
                p[0] = v[kk][0] & 0xBFFFBFFFu; p[1] = v[kk][1] & 0xBFFFBFFFu;
                p[2] = v[kk][2] & 0xBFFFBFFFu; p[3] = v[kk][3] & 0xBFFFBFFFu;
                const f16x8 a = __builtin_bit_cast(f16x8, p);
                #pragma unroll
                for (int ns = 0; ns < 4; ++ns)
                    acc[ns] = __builtin_amdgcn_mfma_f32_16x16x32_f16(a, bfr[ns][kk], acc[ns], 0, 0, 0);
            }
        }

        // ---- prefetch NEXT step's drive terms (latency hides under reduce/barrier) ----
        const int tn = (t + 1 < T_STEPS) ? (t + 1) : t;
        const size_t ion = (size_t)tn * BN + (size_t)grow * NNEUR + gcol;
        const float4 in_n = *(const float4*)(inp + ion);
        const float4 nz_n = *(const float4*)(nz + ion);

        const int pb2 = t & 1;
        #pragma unroll
        for (int ns = 0; ns < 4; ++ns)
            #pragma unroll
            for (int r = 0; r < 4; ++r)
                part[pb2][w][(lq << 2) + r][(ns << 4) + l15] = acc[ns][r];

        __syncthreads();

        f32x4 s = *(const f32x4*)&part[pb2][0][orow][ocol];
        #pragma unroll
        for (int wv2 = 1; wv2 < 4; ++wv2)
            s += *(const f32x4*)&part[pb2][wv2][orow][ocol];

        x0 = 0.9f * x0 + 0.1f * (s[0] + in4.x + b4.x) + 0.003f * nz4.x;
        x1 = 0.9f * x1 + 0.1f * (s[1] + in4.y + b4.y) + 0.003f * nz4.y;
        x2 = 0.9f * x2 + 0.1f * (s[2] + in4.z + b4.z) + 0.003f * nz4.z;
        x3 = 0.9f * x3 + 0.1f * (s[3] + in4.w + b4.w) + 0.003f * nz4.w;

        const float r0 = fast_tanh(x0), r1 = fast_tanh(x1),
                    r2 = fast_tanh(x2), r3 = fast_tanh(x3);

        {   // publish FIRST (consumers wait on these words): 2 packed words + epoch bits
            const unsigned e2m = (((unsigned)(t + 2) >> 1) & 1u) ? 0x40004000u : 0u;
            const unsigned h0 = (unsigned)__builtin_bit_cast(unsigned short, (_Float16)r0);
            const unsigned h1 = (unsigned)__builtin_bit_cast(unsigned short, (_Float16)r1);
            const unsigned h2 = (unsigned)__builtin_bit_cast(unsigned short, (_Float16)r2);
            const unsigned h3 = (unsigned)__builtin_bit_cast(unsigned short, (_Float16)r3);
            u32x2 pw;
            pw[0] = (h0 | (h1 << 16)) | e2m;
            pw[1] = (h2 | (h3 << 16)) | e2m;
            st_u2_dev(wslot + (size_t)((t + 2) & 1) * RING_PACK, pw);
        }
        *(float4*)(out + (size_t)(t + 1) * BN + (size_t)grow * NNEUR + gcol)
            = make_float4(r0, r1, r2, r3);

        in4 = in_n; nz4 = nz_n;
    }
}

// ================= SLOW kernel: R4-proven sc0sc1 + flags (4KB ws footprint) =============
__global__ void __launch_bounds__(256, 1)
rnn_slow(const float* __restrict__ inp, const float* __restrict__ nz,
         const float* __restrict__ W, const float* __restrict__ bias,
         const void* __restrict__ mask, unsigned* flags, float* out) {
    const int bid  = blockIdx.x;
    const int g    = bid & 15;
    const int m    = bid >> 4;
    const int tid  = threadIdx.x;
    const int w    = tid >> 6;
    const int lane = tid & 63;
    const int l15  = lane & 15;
    const int lq   = lane >> 4;

    __shared__ __align__(16) float part[2][4][16][68];

    bool mask_f32, mask_u8;
    detect_mask(mask, lane, mask_f32, mask_u8);
    f16x8 bfr[4][8];
    build_bfr(W, mask, mask_f32, mask_u8, m, w, l15, lq, bfr);

    const int orow = tid >> 4;
    const int ocol = (tid & 15) << 2;
    const int grow = 16 * g + orow;
    const int gcol = 64 * m + ocol;
    const float4 b4 = *(const float4*)(bias + gcol);

    float x0 = 0.f, x1 = 0.f, x2 = 0.f, x3 = 0.f;

    unsigned* const myflag  = &flags[(g << 6) + (m << 2) + w];
    unsigned* const myflags = flags + (g << 6) + (w << 4);

    {
        f32x4 z = {0.f, 0.f, 0.f, 0.f};
        st_f4_dev(out + (size_t)grow * NNEUR + gcol, z);
    }
    drain_vm();
    __builtin_amdgcn_sched_barrier(0);
    if (lane == 0) st_dw_dev(myflag, 1u);

    for (int t = 0; t < T_STEPS; ++t) {
        const size_t io = (size_t)t * BN + (size_t)grow * NNEUR + gcol;
        const float4 in4 = *(const float4*)(inp + io);
        const float4 nz4 = *(const float4*)(nz + io);

        {
            const unsigned tgt = (unsigned)(t + 1);
            if (lane < 16) {
                const unsigned* fp = &myflags[lane];
                int spin = 0;
                unsigned v;
                do {
                    v = ld_dw_dev(fp);
                    if (v >= tgt) break;
                    __builtin_amdgcn_s_sleep(1);
                } while (++spin < (1 << 14));
            }
            __builtin_amdgcn_sched_barrier(0);
        }

        f32x4 alo[8], ahi[8];
        {
            const float* ab = out + (size_t)t * BN + (size_t)(16 * g + l15) * NNEUR
                              + 256 * w + 8 * lq;
            #pragma unroll
            for (int kk = 0; kk < 8; ++kk) {
                alo[kk] = ld_f4_dev(ab + 32 * kk);
                ahi[kk] = ld_f4_dev(ab + 32 * kk + 4);
            }
        }
        drain_vm();
        __builtin_amdgcn_sched_barrier(0);

        f16x8 a[8];
        #pragma unroll
        for (int kk = 0; kk < 8; ++kk) {
            f16x8 av;
            av[0] = (_Float16)alo[kk][0]; av[1] = (_Float16)alo[kk][1];
            av[2] = (_Float16)alo[kk][2]; av[3] = (_Float16)alo[kk][3];
            av[4] = (_Float16)ahi[kk][0]; av[5] = (_Float16)ahi[kk][1];
            av[6] = (_Float16)ahi[kk][2]; av[7] = (_Float16)ahi[kk][3];
            a[kk] = av;
        }

        f32x4 acc[4] = {};
        #pragma unroll
        for (int kk = 0; kk < 8; ++kk)
            #pragma unroll
            for (int ns = 0; ns < 4; ++ns)
                acc[ns] = __builtin_amdgcn_mfma_f32_16x16x32_f16(a[kk], bfr[ns][kk], acc[ns], 0, 0, 0);

        const int pb = t & 1;
        #pragma unroll
        for (int ns = 0; ns < 4; ++ns)
            #pragma unroll
            for (int r = 0; r < 4; ++r)
                part[pb][w][(lq << 2) + r][(ns << 4) + l15] = acc[ns][r];

        __syncthreads();

        f32x4 s = *(const f32x4*)&part[pb][0][orow][ocol];
        #pragma unroll
        for (int wv = 1; wv < 4; ++wv)
            s += *(const f32x4*)&part[pb][wv][orow][ocol];

        x0 = 0.9f * x0 + 0.1f * (s[0] + in4.x + b4.x) + 0.003f * nz4.x;
        x1 = 0.9f * x1 + 0.1f * (s[1] + in4.y + b4.y) + 0.003f * nz4.y;
        x2 = 0.9f * x2 + 0.1f * (s[2] + in4.z + b4.z) + 0.003f * nz4.z;
        x3 = 0.9f * x3 + 0.1f * (s[3] + in4.w + b4.w) + 0.003f * nz4.w;

        {
            f32x4 rv = {tanhf(x0), tanhf(x1), tanhf(x2), tanhf(x3)};
            st_f4_dev(out + (size_t)(t + 1) * BN + (size_t)grow * NNEUR + gcol, rv);
        }
        drain_vm();
        __builtin_amdgcn_sched_barrier(0);
        if (lane == 0) st_dw_dev(myflag, (unsigned)(t + 2));
    }
}

extern "C" void kernel_launch(void* const* d_in, const int* in_sizes, int n_in,
                              void* d_out, int out_size, void* d_ws, size_t ws_size,
                              hipStream_t stream) {
    const float* inp  = (const float*)d_in[0];
    const float* nz   = (const float*)d_in[1];
    const float* W    = (const float*)d_in[2];
    const float* bias = (const float*)d_in[3];
    const void*  mask = d_in[4];
    float* out = (float*)d_out;

    const size_t ring_bytes = (size_t)2 * RING_PACK * sizeof(unsigned);  // 1 MiB
    unsigned* ws = (unsigned*)d_ws;
    void* args[] = {(void*)&inp, (void*)&nz, (void*)&W, (void*)&bias,
                    (void*)&mask, (void*)&ws, (void*)&out};

    if (ws_size >= ring_bytes) {
        // packed epoch-tag ring. Zero every call (init epoch 0 = stale for first visits).
        (void)hipMemsetAsync(ws, 0, ring_bytes, stream);
        hipError_t e = hipLaunchCooperativeKernel((const void*)rnn_fast,
                                                  dim3(256), dim3(256), args, 0, stream);
        if (e != hipSuccess)
            rnn_fast<<<dim3(256), dim3(256), 0, stream>>>(inp, nz, W, bias, mask, ws, out);
    } else {
        // R4-proven slow path: flags only, 4 KiB
        (void)hipMemsetAsync(ws, 0, 4096, stream);
        hipError_t e = hipLaunchCooperativeKernel((const void*)rnn_slow,
                                                  dim3(256), dim3(256), args, 0, stream);
        if (e != hipSuccess)
            rnn_slow<<<dim3(256), dim3(256), 0, stream>>>(inp, nz, W, bias, mask, ws, out);
    }
}